// Round 11
// baseline (427.919 us; speedup 1.0000x reference)
//
#include <hip/hip_runtime.h>
#include <math.h>

#define N_USERS 100000
#define N_ITEMS 40000
#define N_NODES (N_USERS + N_ITEMS)
#define EMB 128
#define EMBQ (EMB / 4)            /* 32 uints of packed 4x fp8 per row */
#define EMBH (EMB / 2)            /* 64 uints of packed 2x bf16 per row */
#define BATCH 8192
#define N_EDGES 1000000
#define N_LAYERS 3
#define ALPHA 0.1f
#define GAMMA 0.01f
#define NGRP 8                    /* one group per XCD (blockIdx % 8 heuristic) */
#define FP8_SCALE 32.0f
#define INV_FP8_SCALE (1.0f / FP8_SCALE)

#define CSRU_MAX (N_EDGES + 8 * N_USERS)   /* u16 entries */
#define CSRI_MAX (N_EDGES + 8 * N_ITEMS)   /* u32 entries */

#define SCAN_BLOCKS 256
#define CHUNK_U ((N_USERS + SCAN_BLOCKS - 1) / SCAN_BLOCKS)   /* 391 */
#define PT_U 2
#define CHUNK_I ((N_ITEMS + SCAN_BLOCKS - 1) / SCAN_BLOCKS)   /* 157 */
#define PT_I 1

typedef float f32x2 __attribute__((ext_vector_type(2)));

// ---------- bf16 pack/unpack (RNE) -------------------------------------------
__device__ inline unsigned int f2bf(float x) {
    const unsigned int b = __float_as_uint(x);
    return (b + 0x7FFFu + ((b >> 16) & 1u)) >> 16;
}
__device__ inline float bfl(unsigned int w) { return __uint_as_float(w << 16); }
__device__ inline float bfh(unsigned int w) { return __uint_as_float(w & 0xFFFF0000u); }

__device__ inline int grp_u(int u) { return (int)(((long long)u * NGRP) / N_USERS); }
__device__ inline int grp_i(int v) { return (int)(((long long)v * NGRP) / N_ITEMS); }

// ---------------- degree histogram (XCD-grouped per side, nt loads) -----------
__global__ void hist_kernel(const int* __restrict__ edge_user,
                            const int* __restrict__ edge_item,
                            int* __restrict__ deg) {
    const int g = blockIdx.x & (NGRP - 1);
    int i = (blockIdx.x >> 3) * blockDim.x + threadIdx.x;
    const int stride = (gridDim.x >> 3) * blockDim.x;
    for (; i < N_EDGES; i += stride) {
        const int u = __builtin_nontemporal_load(&edge_user[i]);
        const int v = __builtin_nontemporal_load(&edge_item[i]);
        if (grp_u(u) == g) atomicAdd(&deg[u], 1);
        if (grp_i(v) == g) atomicAdd(&deg[N_USERS + v], 1);
    }
}

// ---------------- scan phase 1: per-block sums of PADDED degrees --------------
template<int N, int CHUNK, int PT>
__global__ void partial_t(const int* __restrict__ deg, int* __restrict__ bsum) {
    const int b = blockIdx.x;
    const int t = threadIdx.x;
    const int base = b * CHUNK + t * PT;
    const int lim = min((b + 1) * CHUNK, N);
    int s = 0;
    #pragma unroll
    for (int k = 0; k < PT; ++k) {
        const int i = base + k;
        if (i < lim) s += (deg[i] + 7) & ~7;
    }
    __shared__ int red[4];
    #pragma unroll
    for (int off = 32; off > 0; off >>= 1) s += __shfl_down(s, off);
    const int lane = t & 63, wid = t >> 6;
    if (lane == 0) red[wid] = s;
    __syncthreads();
    if (t == 0) bsum[b] = red[0] + red[1] + red[2] + red[3];
}

// ---------------- scan phase 2: scan 256 block sums ---------------------------
__global__ void scanb_kernel(const int* __restrict__ bsum, int* __restrict__ boff,
                             int* __restrict__ total_out) {
    const int t = threadIdx.x;        // 256 threads
    const int lane = t & 63, wid = t >> 6;
    const int v = bsum[t];
    int x = v;
    #pragma unroll
    for (int off = 1; off < 64; off <<= 1) {
        const int y = __shfl_up(x, off);
        if (lane >= off) x += y;
    }
    __shared__ int wtot[4];
    if (lane == 63) wtot[wid] = x;
    __syncthreads();
    int wo = 0;
    for (int k = 0; k < wid; ++k) wo += wtot[k];
    boff[t] = wo + x - v;
    if (t == 255) *total_out = wo + x;   // padded nnz total for this side
}

// -------- scan phase 3: emit row_start/row_cur/inv_sqrt + pad fill ------------
template<int N, int CHUNK, int PT, bool USER>
__global__ void emit_t(const int* __restrict__ deg, const int* __restrict__ boff,
                       int* __restrict__ row_start, int* __restrict__ row_cur,
                       float* __restrict__ isq, void* __restrict__ csr) {
    const int b = blockIdx.x;
    const int t = threadIdx.x;
    const int lane = t & 63, wid = t >> 6;
    const int base = b * CHUNK + t * PT;
    const int lim = min((b + 1) * CHUNK, N);
    int d[PT], dp[PT];
    int s = 0;
    #pragma unroll
    for (int k = 0; k < PT; ++k) {
        const int i = base + k;
        d[k]  = (i < lim) ? deg[i] : 0;
        dp[k] = (d[k] + 7) & ~7;
        s += dp[k];
    }
    int x = s;
    #pragma unroll
    for (int off = 1; off < 64; off <<= 1) {
        const int y = __shfl_up(x, off);
        if (lane >= off) x += y;
    }
    __shared__ int wtot[4];
    if (lane == 63) wtot[wid] = x;
    __syncthreads();
    int wo = boff[b];
    for (int k = 0; k < wid; ++k) wo += wtot[k];
    int p = wo + x - s;
    #pragma unroll
    for (int k = 0; k < PT; ++k) {
        const int i = base + k;
        if (i < lim) {
            row_start[i] = p;
            row_cur[i]   = p;
            isq[i]       = (d[k] > 0) ? (1.0f / sqrtf((float)d[k])) : 0.0f;
            for (int q = d[k]; q < dp[k]; ++q) {
                if (USER) ((unsigned short*)csr)[p + q] = (unsigned short)N_ITEMS;
                else      ((int*)csr)[p + q] = N_USERS;
            }
            p += dp[k];
        }
    }
}

// ---------------- scatter: build BOTH side CSRs (XCD-grouped, nt loads) -------
__global__ void scatter_kernel(const int* __restrict__ edge_user,
                               const int* __restrict__ edge_item,
                               int* __restrict__ row_cur_u,
                               int* __restrict__ row_cur_i,
                               unsigned short* __restrict__ csr_u,
                               int* __restrict__ csr_i) {
    const int g = blockIdx.x & (NGRP - 1);
    int i = (blockIdx.x >> 3) * blockDim.x + threadIdx.x;
    const int stride = (gridDim.x >> 3) * blockDim.x;
    for (; i < N_EDGES; i += stride) {
        const int u = __builtin_nontemporal_load(&edge_user[i]);
        const int v = __builtin_nontemporal_load(&edge_item[i]);
        if (grp_u(u) == g) {
            const int pos = atomicAdd(&row_cur_u[u], 1);
            csr_u[pos] = (unsigned short)v;
        }
        if (grp_i(v) == g) {
            const int pos = atomicAdd(&row_cur_i[v], 1);
            csr_i[pos] = u;
        }
    }
}

// ---------------- zero dummy rows of all 8 fp8 tables -------------------------
__global__ void zero_rows_kernel(unsigned int* __restrict__ e0u, unsigned int* __restrict__ e1u,
                                 unsigned int* __restrict__ e2u, unsigned int* __restrict__ e3u,
                                 unsigned int* __restrict__ e0i, unsigned int* __restrict__ e1i,
                                 unsigned int* __restrict__ e2i, unsigned int* __restrict__ e3i) {
    const int t = threadIdx.x;   // 256 threads: 8 buffers x 32 words
    unsigned int* bufs[8] = {e0u, e1u, e2u, e3u, e0i, e1i, e2i, e3i};
    const int b = t >> 5;
    const size_t row = (b < 4) ? (size_t)N_USERS : (size_t)N_ITEMS;
    bufs[b][row * EMBQ + (t & 31)] = 0u;
}

// -------- init: e0{u,i} = fp8(S * isq * x0); x0b = bf16(x0) -------------------
__global__ void init_kernel(const float* __restrict__ user_emb,
                            const float* __restrict__ item_emb,
                            const float* __restrict__ isq_u,
                            const float* __restrict__ isq_i,
                            unsigned int* __restrict__ e0u,
                            unsigned int* __restrict__ e0i,
                            unsigned int* __restrict__ x0b) {
    const int total = N_NODES * EMBQ;
    const int utotal = N_USERS * EMBQ;
    int i = blockIdx.x * blockDim.x + threadIdx.x;
    const int stride = gridDim.x * blockDim.x;
    for (; i < total; i += stride) {
        const int node = i >> 5;           // /EMBQ
        const int q    = i & 31;
        float4 v; float n;
        if (node < N_USERS) {
            v = ((const float4*)(user_emb + (size_t)node * EMB))[q];
            n = FP8_SCALE * isq_u[node];
        } else {
            v = ((const float4*)(item_emb + (size_t)(node - N_USERS) * EMB))[q];
            n = FP8_SCALE * isq_i[node - N_USERS];
        }
        int pk = __builtin_amdgcn_cvt_pk_fp8_f32(n * v.x, n * v.y, 0, false);
        pk = __builtin_amdgcn_cvt_pk_fp8_f32(n * v.z, n * v.w, pk, true);
        if (node < N_USERS) e0u[i] = (unsigned int)pk;
        else                e0i[i - utotal] = (unsigned int)pk;
        const size_t xb = (size_t)node * EMBH + q * 2;
        x0b[xb]     = f2bf(v.x) | (f2bf(v.y) << 16);
        x0b[xb + 1] = f2bf(v.z) | (f2bf(v.w) << 16);
    }
}

// ---------------- SpMM user side: gathers ITEM table (5.1 MB, L2-hot) ---------
__global__ void spmm_u_kernel(const unsigned int* __restrict__ cur_i,
                              unsigned int* __restrict__ nxt_u,
                              const int* __restrict__ rs_u,
                              const unsigned short* __restrict__ csr_u,
                              const float* __restrict__ isq_u) {
    const int lane = threadIdx.x & 63;
    const int half = lane >> 5;
    const int sub  = lane & 31;
    const int w = blockIdx.x * (blockDim.x >> 6) + (threadIdx.x >> 6);
    if (w >= N_USERS) return;
    const int beg = rs_u[w];
    const int end = rs_u[w + 1];            // padded: multiple of 8
    float s0 = 0.f, s1 = 0.f, s2 = 0.f, s3 = 0.f;
    for (int j = beg + half; j < end; j += 8) {
        const int c0 = csr_u[j];
        const int c1 = csr_u[j + 2];
        const int c2 = csr_u[j + 4];
        const int c3 = csr_u[j + 6];
        const unsigned int v0 = cur_i[(size_t)c0 * EMBQ + sub];
        const unsigned int v1 = cur_i[(size_t)c1 * EMBQ + sub];
        const unsigned int v2 = cur_i[(size_t)c2 * EMBQ + sub];
        const unsigned int v3 = cur_i[(size_t)c3 * EMBQ + sub];
        const f32x2 l0 = __builtin_amdgcn_cvt_pk_f32_fp8((int)v0, false);
        const f32x2 h0 = __builtin_amdgcn_cvt_pk_f32_fp8((int)v0, true);
        const f32x2 l1 = __builtin_amdgcn_cvt_pk_f32_fp8((int)v1, false);
        const f32x2 h1 = __builtin_amdgcn_cvt_pk_f32_fp8((int)v1, true);
        const f32x2 l2 = __builtin_amdgcn_cvt_pk_f32_fp8((int)v2, false);
        const f32x2 h2 = __builtin_amdgcn_cvt_pk_f32_fp8((int)v2, true);
        const f32x2 l3 = __builtin_amdgcn_cvt_pk_f32_fp8((int)v3, false);
        const f32x2 h3 = __builtin_amdgcn_cvt_pk_f32_fp8((int)v3, true);
        s0 += (l0.x + l1.x) + (l2.x + l3.x);
        s1 += (l0.y + l1.y) + (l2.y + l3.y);
        s2 += (h0.x + h1.x) + (h2.x + h3.x);
        s3 += (h0.y + h1.y) + (h2.y + h3.y);
    }
    s0 += __shfl_down(s0, 32);
    s1 += __shfl_down(s1, 32);
    s2 += __shfl_down(s2, 32);
    s3 += __shfl_down(s3, 32);
    if (half == 0) {
        const float n = isq_u[w];
        const float sc = n * n;
        int pk = __builtin_amdgcn_cvt_pk_fp8_f32(sc * s0, sc * s1, 0, false);
        pk = __builtin_amdgcn_cvt_pk_fp8_f32(sc * s2, sc * s3, pk, true);
        nxt_u[(size_t)w * EMBQ + sub] = (unsigned int)pk;
    }
}

// ---------------- SpMM item side: gathers USER table (12.8 MB) ----------------
__global__ void spmm_i_kernel(const unsigned int* __restrict__ cur_u,
                              unsigned int* __restrict__ nxt_i,
                              const int* __restrict__ rs_i,
                              const int* __restrict__ csr_i,
                              const float* __restrict__ isq_i) {
    const int lane = threadIdx.x & 63;
    const int half = lane >> 5;
    const int sub  = lane & 31;
    const int w = blockIdx.x * (blockDim.x >> 6) + (threadIdx.x >> 6);
    if (w >= N_ITEMS) return;
    const int beg = rs_i[w];
    const int end = rs_i[w + 1];            // padded: multiple of 8
    float s0 = 0.f, s1 = 0.f, s2 = 0.f, s3 = 0.f;
    for (int j = beg + half; j < end; j += 8) {
        const int c0 = csr_i[j];
        const int c1 = csr_i[j + 2];
        const int c2 = csr_i[j + 4];
        const int c3 = csr_i[j + 6];
        const unsigned int v0 = cur_u[(size_t)c0 * EMBQ + sub];
        const unsigned int v1 = cur_u[(size_t)c1 * EMBQ + sub];
        const unsigned int v2 = cur_u[(size_t)c2 * EMBQ + sub];
        const unsigned int v3 = cur_u[(size_t)c3 * EMBQ + sub];
        const f32x2 l0 = __builtin_amdgcn_cvt_pk_f32_fp8((int)v0, false);
        const f32x2 h0 = __builtin_amdgcn_cvt_pk_f32_fp8((int)v0, true);
        const f32x2 l1 = __builtin_amdgcn_cvt_pk_f32_fp8((int)v1, false);
        const f32x2 h1 = __builtin_amdgcn_cvt_pk_f32_fp8((int)v1, true);
        const f32x2 l2 = __builtin_amdgcn_cvt_pk_f32_fp8((int)v2, false);
        const f32x2 h2 = __builtin_amdgcn_cvt_pk_f32_fp8((int)v2, true);
        const f32x2 l3 = __builtin_amdgcn_cvt_pk_f32_fp8((int)v3, false);
        const f32x2 h3 = __builtin_amdgcn_cvt_pk_f32_fp8((int)v3, true);
        s0 += (l0.x + l1.x) + (l2.x + l3.x);
        s1 += (l0.y + l1.y) + (l2.y + l3.y);
        s2 += (h0.x + h1.x) + (h2.x + h3.x);
        s3 += (h0.y + h1.y) + (h2.y + h3.y);
    }
    s0 += __shfl_down(s0, 32);
    s1 += __shfl_down(s1, 32);
    s2 += __shfl_down(s2, 32);
    s3 += __shfl_down(s3, 32);
    if (half == 0) {
        const float n = isq_i[w];
        const float sc = n * n;
        int pk = __builtin_amdgcn_cvt_pk_fp8_f32(sc * s0, sc * s1, 0, false);
        pk = __builtin_amdgcn_cvt_pk_fp8_f32(sc * s2, sc * s3, pk, true);
        nxt_i[(size_t)w * EMBQ + sub] = (unsigned int)pk;
    }
}

__device__ inline float logsigmoidf(float x) {
    return (x >= 0.f) ? -log1pf(expf(-x)) : (x - log1pf(expf(x)));
}

// ---------------- fused losses ------------------------------------------------
__global__ void loss_kernel(const unsigned int* __restrict__ x0b,
                            const unsigned short* __restrict__ e1u,
                            const unsigned short* __restrict__ e2u,
                            const unsigned short* __restrict__ e3u,
                            const unsigned short* __restrict__ e1i,
                            const unsigned short* __restrict__ e2i,
                            const unsigned short* __restrict__ e3i,
                            const int* __restrict__ deg,
                            const int* __restrict__ users,
                            const int* __restrict__ pos_items,
                            const int* __restrict__ neg_items,
                            const int* __restrict__ sampled_user,
                            const int* __restrict__ sampled_items,
                            float* __restrict__ sums) {
    const int lane = threadIdx.x & 63;     // dims 2*lane, 2*lane+1
    const int wid  = threadIdx.x >> 6;     // 0..3
    const int gw   = blockIdx.x * 4 + wid;
    const int nw   = gridDim.x * 4;
    float s_bce = 0.f, s_pred = 0.f, s_plogp = 0.f, s_ul = 0.f;
    for (int p = gw; p < 4 * BATCH; p += nw) {
        int u, it;
        if (p < 2 * BATCH) {
            if (p < BATCH) { u = users[p];          it = pos_items[p]; }
            else           { u = users[p - BATCH];  it = neg_items[p - BATCH]; }
        } else {
            const int q = p - 2 * BATCH;
            u = sampled_user[q]; it = sampled_items[q];
        }
        const float sdu = sqrtf((float)deg[u]) * INV_FP8_SCALE;
        const unsigned int a0 = x0b[(size_t)u * EMBH + lane];
        const size_t ui = (size_t)u * 64 + lane;
        const f32x2 u1 = __builtin_amdgcn_cvt_pk_f32_fp8((int)e1u[ui], false);
        const f32x2 u2 = __builtin_amdgcn_cvt_pk_f32_fp8((int)e2u[ui], false);
        const f32x2 u3 = __builtin_amdgcn_cvt_pk_f32_fp8((int)e3u[ui], false);
        const float ax = bfl(a0) + sdu * (u1.x + u2.x + u3.x);
        const float ay = bfh(a0) + sdu * (u1.y + u2.y + u3.y);
        const float sdi = sqrtf((float)deg[N_USERS + it]) * INV_FP8_SCALE;
        const unsigned int b0 = x0b[(size_t)(N_USERS + it) * EMBH + lane];
        const size_t ii = (size_t)it * 64 + lane;
        const f32x2 i1 = __builtin_amdgcn_cvt_pk_f32_fp8((int)e1i[ii], false);
        const f32x2 i2 = __builtin_amdgcn_cvt_pk_f32_fp8((int)e2i[ii], false);
        const f32x2 i3 = __builtin_amdgcn_cvt_pk_f32_fp8((int)e3i[ii], false);
        const float bx = bfl(b0) + sdi * (i1.x + i2.x + i3.x);
        const float by = bfh(b0) + sdi * (i1.y + i2.y + i3.y);
        float d = ax * bx + ay * by;
        #pragma unroll
        for (int off = 32; off > 0; off >>= 1) d += __shfl_down(d, off);
        if (lane == 0) {
            d *= (1.f / 16.f);                  // (acc/4)·(acc/4)
            const float pred = 1.f / (1.f + expf(-d));
            if (p < 2 * BATCH) {
                const float ls  = logsigmoidf(d);
                const float lsn = logsigmoidf(-d);
                s_bce   += (p < BATCH) ? -ls : -lsn;
                s_pred  += pred;
                s_plogp += pred * ls;
            } else {
                s_ul += pred;
            }
        }
    }
    __shared__ float red[4][4];
    if (lane == 0) {
        red[wid][0] = s_bce; red[wid][1] = s_pred;
        red[wid][2] = s_plogp; red[wid][3] = s_ul;
    }
    __syncthreads();
    if (threadIdx.x < 4) {
        const float v = red[0][threadIdx.x] + red[1][threadIdx.x]
                      + red[2][threadIdx.x] + red[3][threadIdx.x];
        atomicAdd(&sums[threadIdx.x], v);
    }
}

// ---------------- finalize ----------------------------------------------------
__global__ void finalize_kernel(const float* __restrict__ sums, float* __restrict__ out) {
    if (threadIdx.x == 0 && blockIdx.x == 0) {
        const float n = 2.f * BATCH;
        const float bce        = sums[0] / n;
        const float pred_avg   = sums[1] / n;
        const float plogp_avg  = sums[2] / n;
        const float predul_avg = sums[3] / n;
        const float info = ALPHA * (-pred_avg * logf(predul_avg)
                                    - (1.f - pred_avg) * logf(1.f - predul_avg))
                         + GAMMA * plogp_avg;
        out[0] = bce;
        out[1] = info;
    }
}

extern "C" void kernel_launch(void* const* d_in, const int* in_sizes, int n_in,
                              void* d_out, int out_size, void* d_ws, size_t ws_size,
                              hipStream_t stream) {
    const float* user_emb      = (const float*)d_in[0];
    const float* item_emb      = (const float*)d_in[1];
    const int*   edge_user     = (const int*)d_in[3];
    const int*   edge_item     = (const int*)d_in[4];
    const int*   users         = (const int*)d_in[5];
    const int*   pos_items     = (const int*)d_in[6];
    const int*   neg_items     = (const int*)d_in[7];
    const int*   sampled_user  = (const int*)d_in[8];
    const int*   sampled_items = (const int*)d_in[9];
    float* out = (float*)d_out;

    const size_t ebu = (size_t)(N_USERS + 1) * EMBQ * sizeof(unsigned int); // 12.8 MB
    const size_t ebi = (size_t)(N_ITEMS + 1) * EMBQ * sizeof(unsigned int); //  5.1 MB
    char* ws = (char*)d_ws;
    size_t off = 0;
    unsigned int* e0u = (unsigned int*)(ws + off); off += ebu;
    unsigned int* e1u = (unsigned int*)(ws + off); off += ebu;
    unsigned int* e2u = (unsigned int*)(ws + off); off += ebu;
    unsigned int* e3u = (unsigned int*)(ws + off); off += ebu;
    unsigned int* e0i = (unsigned int*)(ws + off); off += ebi;
    unsigned int* e1i = (unsigned int*)(ws + off); off += ebi;
    unsigned int* e2i = (unsigned int*)(ws + off); off += ebi;
    unsigned int* e3i = (unsigned int*)(ws + off); off += ebi;
    unsigned int* x0b = (unsigned int*)(ws + off); off += (size_t)N_NODES * EMBH * 4;
    float* sums = (float*)(ws + off); off += 256;
    int*   deg   = (int*)(ws + off); off += (size_t)N_NODES * 4;
    int*   rs_u  = (int*)(ws + off); off += (size_t)(N_USERS + 1) * 4 + 252;
    int*   rc_u  = (int*)(ws + off); off += (size_t)N_USERS * 4;
    int*   rs_i  = (int*)(ws + off); off += (size_t)(N_ITEMS + 1) * 4 + 252;
    int*   rc_i  = (int*)(ws + off); off += (size_t)N_ITEMS * 4;
    float* isq_u = (float*)(ws + off); off += (size_t)N_USERS * 4;
    float* isq_i = (float*)(ws + off); off += (size_t)N_ITEMS * 4;
    unsigned short* csr_u = (unsigned short*)(ws + off); off += (size_t)CSRU_MAX * 2 + 256;
    int*   csr_i = (int*)(ws + off); off += (size_t)CSRI_MAX * 4;
    int*   bsum_u = (int*)(ws + off); off += SCAN_BLOCKS * 4;
    int*   boff_u = (int*)(ws + off); off += SCAN_BLOCKS * 4;
    int*   bsum_i = (int*)(ws + off); off += SCAN_BLOCKS * 4;
    int*   boff_i = (int*)(ws + off); off += SCAN_BLOCKS * 4;

    hipMemsetAsync(deg, 0, (size_t)N_NODES * 4, stream);
    hipMemsetAsync(sums, 0, 4 * sizeof(float), stream);

    hist_kernel<<<2048, 256, 0, stream>>>(edge_user, edge_item, deg);
    partial_t<N_USERS, CHUNK_U, PT_U><<<SCAN_BLOCKS, 256, 0, stream>>>(deg, bsum_u);
    partial_t<N_ITEMS, CHUNK_I, PT_I><<<SCAN_BLOCKS, 256, 0, stream>>>(deg + N_USERS, bsum_i);
    scanb_kernel<<<1, 256, 0, stream>>>(bsum_u, boff_u, rs_u + N_USERS);
    scanb_kernel<<<1, 256, 0, stream>>>(bsum_i, boff_i, rs_i + N_ITEMS);
    emit_t<N_USERS, CHUNK_U, PT_U, true><<<SCAN_BLOCKS, 256, 0, stream>>>(
        deg, boff_u, rs_u, rc_u, isq_u, (void*)csr_u);
    emit_t<N_ITEMS, CHUNK_I, PT_I, false><<<SCAN_BLOCKS, 256, 0, stream>>>(
        deg + N_USERS, boff_i, rs_i, rc_i, isq_i, (void*)csr_i);
    scatter_kernel<<<2048, 256, 0, stream>>>(edge_user, edge_item, rc_u, rc_i,
                                             csr_u, csr_i);
    zero_rows_kernel<<<1, 256, 0, stream>>>(e0u, e1u, e2u, e3u, e0i, e1i, e2i, e3i);
    init_kernel<<<4096, 256, 0, stream>>>(user_emb, item_emb, isq_u, isq_i,
                                          e0u, e0i, x0b);

    // layer 1..3: user rows gather item table; item rows gather user table
    spmm_u_kernel<<<(N_USERS + 3) / 4, 256, 0, stream>>>(e0i, e1u, rs_u, csr_u, isq_u);
    spmm_i_kernel<<<(N_ITEMS + 3) / 4, 256, 0, stream>>>(e0u, e1i, rs_i, csr_i, isq_i);
    spmm_u_kernel<<<(N_USERS + 3) / 4, 256, 0, stream>>>(e1i, e2u, rs_u, csr_u, isq_u);
    spmm_i_kernel<<<(N_ITEMS + 3) / 4, 256, 0, stream>>>(e1u, e2i, rs_i, csr_i, isq_i);
    spmm_u_kernel<<<(N_USERS + 3) / 4, 256, 0, stream>>>(e2i, e3u, rs_u, csr_u, isq_u);
    spmm_i_kernel<<<(N_ITEMS + 3) / 4, 256, 0, stream>>>(e2u, e3i, rs_i, csr_i, isq_i);

    loss_kernel<<<512, 256, 0, stream>>>(x0b,
                                         (const unsigned short*)e1u,
                                         (const unsigned short*)e2u,
                                         (const unsigned short*)e3u,
                                         (const unsigned short*)e1i,
                                         (const unsigned short*)e2i,
                                         (const unsigned short*)e3i,
                                         deg, users, pos_items, neg_items,
                                         sampled_user, sampled_items, sums);
    finalize_kernel<<<1, 1, 0, stream>>>(sums, out);
}

// Round 12
// 352.379 us; speedup vs baseline: 1.2144x; 1.2144x over previous
//
#include <hip/hip_runtime.h>
#include <math.h>

#define N_USERS 100000
#define N_ITEMS 40000
#define N_NODES (N_USERS + N_ITEMS)
#define EMB 128
#define EMBQ (EMB / 4)            /* 32 uints of packed 4x fp8 per row */
#define EMBH (EMB / 2)            /* 64 uints of packed 2x bf16 per row */
#define BATCH 8192
#define N_EDGES 1000000
#define ALPHA 0.1f
#define GAMMA 0.01f
#define FP8_SCALE 32.0f
#define INV_FP8_SCALE (1.0f / FP8_SCALE)

/* ---- bucket-sort CSR build geometry ---- */
#define RB_U 512                                /* rows per user bucket (shift 9) */
#define NB_U ((N_USERS + RB_U - 1) / RB_U)      /* 196 */
#define RB_I 256                                /* rows per item bucket (shift 8) */
#define NB_I ((N_ITEMS + RB_I - 1) / RB_I)      /* 157 */
#define NB_T (NB_U + NB_I)                      /* 353 */
#define PART_BLOCKS 256

#define CSRU_MAX (N_EDGES + 8 * (NB_U * RB_U))  /* u16 entries */
#define CSRI_MAX (N_EDGES + 8 * (NB_I * RB_I))  /* u32 entries */

typedef float f32x2 __attribute__((ext_vector_type(2)));

// ---------- bf16 pack/unpack (RNE) -------------------------------------------
__device__ inline unsigned int f2bf(float x) {
    const unsigned int b = __float_as_uint(x);
    return (b + 0x7FFFu + ((b >> 16) & 1u)) >> 16;
}
__device__ inline float bfl(unsigned int w) { return __uint_as_float(w << 16); }
__device__ inline float bfh(unsigned int w) { return __uint_as_float(w & 0xFFFF0000u); }

// ============ CSR build, atomic-free (block-private hist + bucket sort) =======

// ---- A: per-block bucket histograms (LDS only) -------------------------------
__global__ void bucketA(const int* __restrict__ eu, const int* __restrict__ ev,
                        int* __restrict__ histA /* [PART_BLOCKS][NB_T] */) {
    __shared__ int h[NB_T];
    for (int k = threadIdx.x; k < NB_T; k += 256) h[k] = 0;
    __syncthreads();
    const int b = blockIdx.x;
    const int beg = (int)((long long)N_EDGES * b / PART_BLOCKS);
    const int end = (int)((long long)N_EDGES * (b + 1) / PART_BLOCKS);
    for (int i = beg + threadIdx.x; i < end; i += 256) {
        const int u = __builtin_nontemporal_load(&eu[i]);
        const int v = __builtin_nontemporal_load(&ev[i]);
        atomicAdd(&h[u >> 9], 1);
        atomicAdd(&h[NB_U + (v >> 8)], 1);
    }
    __syncthreads();
    for (int k = threadIdx.x; k < NB_T; k += 256) histA[b * NB_T + k] = h[k];
}

// ---- B: scan histogram matrix -> per-(block,bucket) absolute offsets ---------
__global__ void bucketB(const int* __restrict__ histA, int* __restrict__ woff,
                        int* __restrict__ bktCnt, int* __restrict__ bktBase) {
    const int k = threadIdx.x;   // 512 threads, k < NB_T active
    if (k < NB_T) {
        int run = 0;
        for (int b = 0; b < PART_BLOCKS; ++b) {
            const int t = histA[b * NB_T + k];
            woff[b * NB_T + k] = run;
            run += t;
        }
        bktCnt[k] = run;
    }
    __syncthreads();
    if (threadIdx.x == 0) {
        int acc = 0;
        for (int q = 0; q < NB_U; ++q) { bktBase[q] = acc; acc += bktCnt[q]; }
        acc = 0;
        for (int q = NB_U; q < NB_T; ++q) { bktBase[q] = acc; acc += bktCnt[q]; }
    }
    __syncthreads();
    if (k < NB_T) {
        const int bb = bktBase[k];
        for (int b = 0; b < PART_BLOCKS; ++b) woff[b * NB_T + k] += bb;
    }
}

// ---- C: partition edges into bucket-contiguous arrays (packed u32) -----------
// pack user-part:  lrow(9b) | v<<9  (v < 40000 -> 25 bits)
// pack item-part:  lrow(8b) | u<<8  (u < 100000 -> 25 bits)
__global__ void bucketC(const int* __restrict__ eu, const int* __restrict__ ev,
                        const int* __restrict__ woff,
                        unsigned int* __restrict__ part_u,
                        unsigned int* __restrict__ part_i) {
    __shared__ int cur[NB_T];
    const int b = blockIdx.x;
    for (int k = threadIdx.x; k < NB_T; k += 256) cur[k] = woff[b * NB_T + k];
    __syncthreads();
    const int beg = (int)((long long)N_EDGES * b / PART_BLOCKS);
    const int end = (int)((long long)N_EDGES * (b + 1) / PART_BLOCKS);
    for (int i = beg + threadIdx.x; i < end; i += 256) {
        const int u = __builtin_nontemporal_load(&eu[i]);
        const int v = __builtin_nontemporal_load(&ev[i]);
        const int pu = atomicAdd(&cur[u >> 9], 1);
        part_u[pu] = (unsigned int)((u & (RB_U - 1)) | (v << 9));
        const int pi = atomicAdd(&cur[NB_U + (v >> 8)], 1);
        part_i[pi] = (unsigned int)((v & (RB_I - 1)) | (u << 8));
    }
}

// ---- D1: per-bucket row degrees -> deg, isq, padded bucket sums --------------
__global__ void csr_d1(const unsigned int* __restrict__ part_u,
                       const unsigned int* __restrict__ part_i,
                       const int* __restrict__ bktBase, const int* __restrict__ bktCnt,
                       int* __restrict__ deg, float* __restrict__ isq_u,
                       float* __restrict__ isq_i, int* __restrict__ bps) {
    const int k = blockIdx.x;
    const bool isU = (k < NB_U);
    const int R = isU ? RB_U : RB_I;
    const int row0 = isU ? k * RB_U : (k - NB_U) * RB_I;
    const int Nside = isU ? N_USERS : N_ITEMS;
    const unsigned int* part = isU ? part_u : part_i;
    const int mask = R - 1;
    __shared__ int dh[RB_U];
    for (int r = threadIdx.x; r < R; r += 256) dh[r] = 0;
    __syncthreads();
    const int base = bktBase[k], cnt = bktCnt[k];
    for (int j = threadIdx.x; j < cnt; j += 256)
        atomicAdd(&dh[part[base + j] & mask], 1);
    __syncthreads();
    const int t = threadIdx.x, lane = t & 63, wid = t >> 6;
    const int r0 = 2 * t, r1 = 2 * t + 1;
    const int d0 = (r0 < R) ? dh[r0] : 0;
    const int d1 = (r1 < R) ? dh[r1] : 0;
    const int v0 = (d0 + 7) & ~7, v1 = (d1 + 7) & ~7;
    const int s = v0 + v1;
    int x = s;
    #pragma unroll
    for (int off = 1; off < 64; off <<= 1) {
        const int y = __shfl_up(x, off);
        if (lane >= off) x += y;
    }
    __shared__ int wtot[4];
    if (lane == 63) wtot[wid] = x;
    __syncthreads();
    if (t == 0) bps[k] = wtot[0] + wtot[1] + wtot[2] + wtot[3];
    if (r0 < R && row0 + r0 < Nside) {
        deg[(isU ? 0 : N_USERS) + row0 + r0] = d0;
        if (isU) isq_u[row0 + r0] = (d0 > 0) ? (1.0f / sqrtf((float)d0)) : 0.f;
        else     isq_i[row0 + r0] = (d0 > 0) ? (1.0f / sqrtf((float)d0)) : 0.f;
    }
    if (r1 < R && row0 + r1 < Nside) {
        deg[(isU ? 0 : N_USERS) + row0 + r1] = d1;
        if (isU) isq_u[row0 + r1] = (d1 > 0) ? (1.0f / sqrtf((float)d1)) : 0.f;
        else     isq_i[row0 + r1] = (d1 > 0) ? (1.0f / sqrtf((float)d1)) : 0.f;
    }
}

// ---- D2: scan padded bucket sums -> csr bases; totals ------------------------
__global__ void csr_d2(const int* __restrict__ bps, int* __restrict__ bcb,
                       int* __restrict__ rs_u, int* __restrict__ rs_i) {
    if (threadIdx.x == 0) {
        int acc = 0;
        for (int k = 0; k < NB_U; ++k) { bcb[k] = acc; acc += bps[k]; }
        rs_u[N_USERS] = acc;
        acc = 0;
        for (int k = NB_U; k < NB_T; ++k) { bcb[k] = acc; acc += bps[k]; }
        rs_i[N_ITEMS] = acc;
    }
}

// ---- D3: write row_start, padding, and rank-scatter cols (LDS atomics only) --
__global__ void csr_d3(const unsigned int* __restrict__ part_u,
                       const unsigned int* __restrict__ part_i,
                       const int* __restrict__ bktBase, const int* __restrict__ bktCnt,
                       const int* __restrict__ bcb,
                       int* __restrict__ rs_u, int* __restrict__ rs_i,
                       unsigned short* __restrict__ csr_u, int* __restrict__ csr_i) {
    const int k = blockIdx.x;
    const bool isU = (k < NB_U);
    const int R = isU ? RB_U : RB_I;
    const int row0 = isU ? k * RB_U : (k - NB_U) * RB_I;
    const int Nside = isU ? N_USERS : N_ITEMS;
    const unsigned int* part = isU ? part_u : part_i;
    const int mask = R - 1;
    const int shift = isU ? 9 : 8;
    __shared__ int dh[RB_U];
    __shared__ int cur[RB_U];
    for (int r = threadIdx.x; r < R; r += 256) dh[r] = 0;
    __syncthreads();
    const int base = bktBase[k], cnt = bktCnt[k];
    for (int j = threadIdx.x; j < cnt; j += 256)
        atomicAdd(&dh[part[base + j] & mask], 1);
    __syncthreads();
    const int t = threadIdx.x, lane = t & 63, wid = t >> 6;
    const int r0 = 2 * t, r1 = 2 * t + 1;
    const int d0 = (r0 < R) ? dh[r0] : 0;
    const int d1 = (r1 < R) ? dh[r1] : 0;
    const int v0 = (d0 + 7) & ~7, v1 = (d1 + 7) & ~7;
    const int s = v0 + v1;
    int x = s;
    #pragma unroll
    for (int off = 1; off < 64; off <<= 1) {
        const int y = __shfl_up(x, off);
        if (lane >= off) x += y;
    }
    __shared__ int wtot[4];
    if (lane == 63) wtot[wid] = x;
    __syncthreads();
    int wo = 0;
    for (int q = 0; q < wid; ++q) wo += wtot[q];
    const int pref = wo + x - s;              // exclusive padded prefix at r0
    const int cb = bcb[k];
    if (r0 < R) {
        const int st = cb + pref;
        cur[r0] = st;
        if (row0 + r0 < Nside) { if (isU) rs_u[row0 + r0] = st; else rs_i[row0 + r0] = st; }
        for (int q = d0; q < v0; ++q) {
            if (isU) csr_u[st + q] = (unsigned short)N_ITEMS; else csr_i[st + q] = N_USERS;
        }
    }
    if (r1 < R) {
        const int st = cb + pref + v0;
        cur[r1] = st;
        if (row0 + r1 < Nside) { if (isU) rs_u[row0 + r1] = st; else rs_i[row0 + r1] = st; }
        for (int q = d1; q < v1; ++q) {
            if (isU) csr_u[st + q] = (unsigned short)N_ITEMS; else csr_i[st + q] = N_USERS;
        }
    }
    __syncthreads();
    for (int j = threadIdx.x; j < cnt; j += 256) {
        const unsigned int e = part[base + j];
        const int pos = atomicAdd(&cur[e & mask], 1);
        const int col = (int)(e >> shift);
        if (isU) csr_u[pos] = (unsigned short)col; else csr_i[pos] = col;
    }
}

// ================== embedding pipeline (unchanged from R11) ===================

__global__ void zero_rows_kernel(unsigned int* __restrict__ e0u, unsigned int* __restrict__ e1u,
                                 unsigned int* __restrict__ e2u, unsigned int* __restrict__ e3u,
                                 unsigned int* __restrict__ e0i, unsigned int* __restrict__ e1i,
                                 unsigned int* __restrict__ e2i, unsigned int* __restrict__ e3i) {
    const int t = threadIdx.x;   // 256 threads: 8 buffers x 32 words
    unsigned int* bufs[8] = {e0u, e1u, e2u, e3u, e0i, e1i, e2i, e3i};
    const int b = t >> 5;
    const size_t row = (b < 4) ? (size_t)N_USERS : (size_t)N_ITEMS;
    bufs[b][row * EMBQ + (t & 31)] = 0u;
}

__global__ void init_kernel(const float* __restrict__ user_emb,
                            const float* __restrict__ item_emb,
                            const float* __restrict__ isq_u,
                            const float* __restrict__ isq_i,
                            unsigned int* __restrict__ e0u,
                            unsigned int* __restrict__ e0i,
                            unsigned int* __restrict__ x0b) {
    const int total = N_NODES * EMBQ;
    const int utotal = N_USERS * EMBQ;
    int i = blockIdx.x * blockDim.x + threadIdx.x;
    const int stride = gridDim.x * blockDim.x;
    for (; i < total; i += stride) {
        const int node = i >> 5;
        const int q    = i & 31;
        float4 v; float n;
        if (node < N_USERS) {
            v = ((const float4*)(user_emb + (size_t)node * EMB))[q];
            n = FP8_SCALE * isq_u[node];
        } else {
            v = ((const float4*)(item_emb + (size_t)(node - N_USERS) * EMB))[q];
            n = FP8_SCALE * isq_i[node - N_USERS];
        }
        int pk = __builtin_amdgcn_cvt_pk_fp8_f32(n * v.x, n * v.y, 0, false);
        pk = __builtin_amdgcn_cvt_pk_fp8_f32(n * v.z, n * v.w, pk, true);
        if (node < N_USERS) e0u[i] = (unsigned int)pk;
        else                e0i[i - utotal] = (unsigned int)pk;
        const size_t xb = (size_t)node * EMBH + q * 2;
        x0b[xb]     = f2bf(v.x) | (f2bf(v.y) << 16);
        x0b[xb + 1] = f2bf(v.z) | (f2bf(v.w) << 16);
    }
}

__global__ void spmm_u_kernel(const unsigned int* __restrict__ cur_i,
                              unsigned int* __restrict__ nxt_u,
                              const int* __restrict__ rs_u,
                              const unsigned short* __restrict__ csr_u,
                              const float* __restrict__ isq_u) {
    const int lane = threadIdx.x & 63;
    const int half = lane >> 5;
    const int sub  = lane & 31;
    const int w = blockIdx.x * (blockDim.x >> 6) + (threadIdx.x >> 6);
    if (w >= N_USERS) return;
    const int beg = rs_u[w];
    const int end = rs_u[w + 1];
    float s0 = 0.f, s1 = 0.f, s2 = 0.f, s3 = 0.f;
    for (int j = beg + half; j < end; j += 8) {
        const int c0 = csr_u[j];
        const int c1 = csr_u[j + 2];
        const int c2 = csr_u[j + 4];
        const int c3 = csr_u[j + 6];
        const unsigned int v0 = cur_i[(size_t)c0 * EMBQ + sub];
        const unsigned int v1 = cur_i[(size_t)c1 * EMBQ + sub];
        const unsigned int v2 = cur_i[(size_t)c2 * EMBQ + sub];
        const unsigned int v3 = cur_i[(size_t)c3 * EMBQ + sub];
        const f32x2 l0 = __builtin_amdgcn_cvt_pk_f32_fp8((int)v0, false);
        const f32x2 h0 = __builtin_amdgcn_cvt_pk_f32_fp8((int)v0, true);
        const f32x2 l1 = __builtin_amdgcn_cvt_pk_f32_fp8((int)v1, false);
        const f32x2 h1 = __builtin_amdgcn_cvt_pk_f32_fp8((int)v1, true);
        const f32x2 l2 = __builtin_amdgcn_cvt_pk_f32_fp8((int)v2, false);
        const f32x2 h2 = __builtin_amdgcn_cvt_pk_f32_fp8((int)v2, true);
        const f32x2 l3 = __builtin_amdgcn_cvt_pk_f32_fp8((int)v3, false);
        const f32x2 h3 = __builtin_amdgcn_cvt_pk_f32_fp8((int)v3, true);
        s0 += (l0.x + l1.x) + (l2.x + l3.x);
        s1 += (l0.y + l1.y) + (l2.y + l3.y);
        s2 += (h0.x + h1.x) + (h2.x + h3.x);
        s3 += (h0.y + h1.y) + (h2.y + h3.y);
    }
    s0 += __shfl_down(s0, 32);
    s1 += __shfl_down(s1, 32);
    s2 += __shfl_down(s2, 32);
    s3 += __shfl_down(s3, 32);
    if (half == 0) {
        const float n = isq_u[w];
        const float sc = n * n;
        int pk = __builtin_amdgcn_cvt_pk_fp8_f32(sc * s0, sc * s1, 0, false);
        pk = __builtin_amdgcn_cvt_pk_fp8_f32(sc * s2, sc * s3, pk, true);
        nxt_u[(size_t)w * EMBQ + sub] = (unsigned int)pk;
    }
}

__global__ void spmm_i_kernel(const unsigned int* __restrict__ cur_u,
                              unsigned int* __restrict__ nxt_i,
                              const int* __restrict__ rs_i,
                              const int* __restrict__ csr_i,
                              const float* __restrict__ isq_i) {
    const int lane = threadIdx.x & 63;
    const int half = lane >> 5;
    const int sub  = lane & 31;
    const int w = blockIdx.x * (blockDim.x >> 6) + (threadIdx.x >> 6);
    if (w >= N_ITEMS) return;
    const int beg = rs_i[w];
    const int end = rs_i[w + 1];
    float s0 = 0.f, s1 = 0.f, s2 = 0.f, s3 = 0.f;
    for (int j = beg + half; j < end; j += 8) {
        const int c0 = csr_i[j];
        const int c1 = csr_i[j + 2];
        const int c2 = csr_i[j + 4];
        const int c3 = csr_i[j + 6];
        const unsigned int v0 = cur_u[(size_t)c0 * EMBQ + sub];
        const unsigned int v1 = cur_u[(size_t)c1 * EMBQ + sub];
        const unsigned int v2 = cur_u[(size_t)c2 * EMBQ + sub];
        const unsigned int v3 = cur_u[(size_t)c3 * EMBQ + sub];
        const f32x2 l0 = __builtin_amdgcn_cvt_pk_f32_fp8((int)v0, false);
        const f32x2 h0 = __builtin_amdgcn_cvt_pk_f32_fp8((int)v0, true);
        const f32x2 l1 = __builtin_amdgcn_cvt_pk_f32_fp8((int)v1, false);
        const f32x2 h1 = __builtin_amdgcn_cvt_pk_f32_fp8((int)v1, true);
        const f32x2 l2 = __builtin_amdgcn_cvt_pk_f32_fp8((int)v2, false);
        const f32x2 h2 = __builtin_amdgcn_cvt_pk_f32_fp8((int)v2, true);
        const f32x2 l3 = __builtin_amdgcn_cvt_pk_f32_fp8((int)v3, false);
        const f32x2 h3 = __builtin_amdgcn_cvt_pk_f32_fp8((int)v3, true);
        s0 += (l0.x + l1.x) + (l2.x + l3.x);
        s1 += (l0.y + l1.y) + (l2.y + l3.y);
        s2 += (h0.x + h1.x) + (h2.x + h3.x);
        s3 += (h0.y + h1.y) + (h2.y + h3.y);
    }
    s0 += __shfl_down(s0, 32);
    s1 += __shfl_down(s1, 32);
    s2 += __shfl_down(s2, 32);
    s3 += __shfl_down(s3, 32);
    if (half == 0) {
        const float n = isq_i[w];
        const float sc = n * n;
        int pk = __builtin_amdgcn_cvt_pk_fp8_f32(sc * s0, sc * s1, 0, false);
        pk = __builtin_amdgcn_cvt_pk_fp8_f32(sc * s2, sc * s3, pk, true);
        nxt_i[(size_t)w * EMBQ + sub] = (unsigned int)pk;
    }
}

__device__ inline float logsigmoidf(float x) {
    return (x >= 0.f) ? -log1pf(expf(-x)) : (x - log1pf(expf(x)));
}

__global__ void loss_kernel(const unsigned int* __restrict__ x0b,
                            const unsigned short* __restrict__ e1u,
                            const unsigned short* __restrict__ e2u,
                            const unsigned short* __restrict__ e3u,
                            const unsigned short* __restrict__ e1i,
                            const unsigned short* __restrict__ e2i,
                            const unsigned short* __restrict__ e3i,
                            const int* __restrict__ deg,
                            const int* __restrict__ users,
                            const int* __restrict__ pos_items,
                            const int* __restrict__ neg_items,
                            const int* __restrict__ sampled_user,
                            const int* __restrict__ sampled_items,
                            float* __restrict__ sums) {
    const int lane = threadIdx.x & 63;
    const int wid  = threadIdx.x >> 6;
    const int gw   = blockIdx.x * 4 + wid;
    const int nw   = gridDim.x * 4;
    float s_bce = 0.f, s_pred = 0.f, s_plogp = 0.f, s_ul = 0.f;
    for (int p = gw; p < 4 * BATCH; p += nw) {
        int u, it;
        if (p < 2 * BATCH) {
            if (p < BATCH) { u = users[p];          it = pos_items[p]; }
            else           { u = users[p - BATCH];  it = neg_items[p - BATCH]; }
        } else {
            const int q = p - 2 * BATCH;
            u = sampled_user[q]; it = sampled_items[q];
        }
        const float sdu = sqrtf((float)deg[u]) * INV_FP8_SCALE;
        const unsigned int a0 = x0b[(size_t)u * EMBH + lane];
        const size_t ui = (size_t)u * 64 + lane;
        const f32x2 u1 = __builtin_amdgcn_cvt_pk_f32_fp8((int)e1u[ui], false);
        const f32x2 u2 = __builtin_amdgcn_cvt_pk_f32_fp8((int)e2u[ui], false);
        const f32x2 u3 = __builtin_amdgcn_cvt_pk_f32_fp8((int)e3u[ui], false);
        const float ax = bfl(a0) + sdu * (u1.x + u2.x + u3.x);
        const float ay = bfh(a0) + sdu * (u1.y + u2.y + u3.y);
        const float sdi = sqrtf((float)deg[N_USERS + it]) * INV_FP8_SCALE;
        const unsigned int b0 = x0b[(size_t)(N_USERS + it) * EMBH + lane];
        const size_t ii = (size_t)it * 64 + lane;
        const f32x2 i1 = __builtin_amdgcn_cvt_pk_f32_fp8((int)e1i[ii], false);
        const f32x2 i2 = __builtin_amdgcn_cvt_pk_f32_fp8((int)e2i[ii], false);
        const f32x2 i3 = __builtin_amdgcn_cvt_pk_f32_fp8((int)e3i[ii], false);
        const float bx = bfl(b0) + sdi * (i1.x + i2.x + i3.x);
        const float by = bfh(b0) + sdi * (i1.y + i2.y + i3.y);
        float d = ax * bx + ay * by;
        #pragma unroll
        for (int off = 32; off > 0; off >>= 1) d += __shfl_down(d, off);
        if (lane == 0) {
            d *= (1.f / 16.f);
            const float pred = 1.f / (1.f + expf(-d));
            if (p < 2 * BATCH) {
                const float ls  = logsigmoidf(d);
                const float lsn = logsigmoidf(-d);
                s_bce   += (p < BATCH) ? -ls : -lsn;
                s_pred  += pred;
                s_plogp += pred * ls;
            } else {
                s_ul += pred;
            }
        }
    }
    __shared__ float red[4][4];
    if (lane == 0) {
        red[wid][0] = s_bce; red[wid][1] = s_pred;
        red[wid][2] = s_plogp; red[wid][3] = s_ul;
    }
    __syncthreads();
    if (threadIdx.x < 4) {
        const float v = red[0][threadIdx.x] + red[1][threadIdx.x]
                      + red[2][threadIdx.x] + red[3][threadIdx.x];
        atomicAdd(&sums[threadIdx.x], v);
    }
}

__global__ void finalize_kernel(const float* __restrict__ sums, float* __restrict__ out) {
    if (threadIdx.x == 0 && blockIdx.x == 0) {
        const float n = 2.f * BATCH;
        const float bce        = sums[0] / n;
        const float pred_avg   = sums[1] / n;
        const float plogp_avg  = sums[2] / n;
        const float predul_avg = sums[3] / n;
        const float info = ALPHA * (-pred_avg * logf(predul_avg)
                                    - (1.f - pred_avg) * logf(1.f - predul_avg))
                         + GAMMA * plogp_avg;
        out[0] = bce;
        out[1] = info;
    }
}

extern "C" void kernel_launch(void* const* d_in, const int* in_sizes, int n_in,
                              void* d_out, int out_size, void* d_ws, size_t ws_size,
                              hipStream_t stream) {
    const float* user_emb      = (const float*)d_in[0];
    const float* item_emb      = (const float*)d_in[1];
    const int*   edge_user     = (const int*)d_in[3];
    const int*   edge_item     = (const int*)d_in[4];
    const int*   users         = (const int*)d_in[5];
    const int*   pos_items     = (const int*)d_in[6];
    const int*   neg_items     = (const int*)d_in[7];
    const int*   sampled_user  = (const int*)d_in[8];
    const int*   sampled_items = (const int*)d_in[9];
    float* out = (float*)d_out;

    const size_t ebu = (size_t)(N_USERS + 1) * EMBQ * sizeof(unsigned int); // 12.8 MB
    const size_t ebi = (size_t)(N_ITEMS + 1) * EMBQ * sizeof(unsigned int); //  5.1 MB
    char* ws = (char*)d_ws;
    size_t off = 0;
    unsigned int* e0u = (unsigned int*)(ws + off); off += ebu;
    unsigned int* e1u = (unsigned int*)(ws + off); off += ebu;
    unsigned int* e2u = (unsigned int*)(ws + off); off += ebu;
    unsigned int* e3u = (unsigned int*)(ws + off); off += ebu;
    unsigned int* e0i = (unsigned int*)(ws + off); off += ebi;
    unsigned int* e1i = (unsigned int*)(ws + off); off += ebi;
    unsigned int* e2i = (unsigned int*)(ws + off); off += ebi;
    unsigned int* e3i = (unsigned int*)(ws + off); off += ebi;
    unsigned int* x0b = (unsigned int*)(ws + off); off += (size_t)N_NODES * EMBH * 4;
    float* sums = (float*)(ws + off); off += 256;
    int*   deg   = (int*)(ws + off); off += (size_t)N_NODES * 4;
    int*   rs_u  = (int*)(ws + off); off += (size_t)(N_USERS + 1) * 4 + 252;
    int*   rs_i  = (int*)(ws + off); off += (size_t)(N_ITEMS + 1) * 4 + 252;
    float* isq_u = (float*)(ws + off); off += (size_t)N_USERS * 4;
    float* isq_i = (float*)(ws + off); off += (size_t)N_ITEMS * 4;
    unsigned short* csr_u = (unsigned short*)(ws + off); off += (size_t)CSRU_MAX * 2 + 256;
    int*   csr_i = (int*)(ws + off); off += (size_t)CSRI_MAX * 4;
    unsigned int* part_u = (unsigned int*)(ws + off); off += (size_t)N_EDGES * 4;
    unsigned int* part_i = (unsigned int*)(ws + off); off += (size_t)N_EDGES * 4;
    int*   histA   = (int*)(ws + off); off += (size_t)PART_BLOCKS * NB_T * 4;
    int*   woff    = (int*)(ws + off); off += (size_t)PART_BLOCKS * NB_T * 4;
    int*   bktCnt  = (int*)(ws + off); off += (size_t)NB_T * 4;
    int*   bktBase = (int*)(ws + off); off += (size_t)NB_T * 4;
    int*   bps     = (int*)(ws + off); off += (size_t)NB_T * 4;
    int*   bcb     = (int*)(ws + off); off += (size_t)NB_T * 4;

    hipMemsetAsync(sums, 0, 4 * sizeof(float), stream);

    bucketA<<<PART_BLOCKS, 256, 0, stream>>>(edge_user, edge_item, histA);
    bucketB<<<1, 512, 0, stream>>>(histA, woff, bktCnt, bktBase);
    bucketC<<<PART_BLOCKS, 256, 0, stream>>>(edge_user, edge_item, woff,
                                             part_u, part_i);
    csr_d1<<<NB_T, 256, 0, stream>>>(part_u, part_i, bktBase, bktCnt,
                                     deg, isq_u, isq_i, bps);
    csr_d2<<<1, 64, 0, stream>>>(bps, bcb, rs_u, rs_i);
    csr_d3<<<NB_T, 256, 0, stream>>>(part_u, part_i, bktBase, bktCnt, bcb,
                                     rs_u, rs_i, csr_u, csr_i);
    zero_rows_kernel<<<1, 256, 0, stream>>>(e0u, e1u, e2u, e3u, e0i, e1i, e2i, e3i);
    init_kernel<<<4096, 256, 0, stream>>>(user_emb, item_emb, isq_u, isq_i,
                                          e0u, e0i, x0b);

    spmm_u_kernel<<<(N_USERS + 3) / 4, 256, 0, stream>>>(e0i, e1u, rs_u, csr_u, isq_u);
    spmm_i_kernel<<<(N_ITEMS + 3) / 4, 256, 0, stream>>>(e0u, e1i, rs_i, csr_i, isq_i);
    spmm_u_kernel<<<(N_USERS + 3) / 4, 256, 0, stream>>>(e1i, e2u, rs_u, csr_u, isq_u);
    spmm_i_kernel<<<(N_ITEMS + 3) / 4, 256, 0, stream>>>(e1u, e2i, rs_i, csr_i, isq_i);
    spmm_u_kernel<<<(N_USERS + 3) / 4, 256, 0, stream>>>(e2i, e3u, rs_u, csr_u, isq_u);
    spmm_i_kernel<<<(N_ITEMS + 3) / 4, 256, 0, stream>>>(e2u, e3i, rs_i, csr_i, isq_i);

    loss_kernel<<<512, 256, 0, stream>>>(x0b,
                                         (const unsigned short*)e1u,
                                         (const unsigned short*)e2u,
                                         (const unsigned short*)e3u,
                                         (const unsigned short*)e1i,
                                         (const unsigned short*)e2i,
                                         (const unsigned short*)e3i,
                                         deg, users, pos_items, neg_items,
                                         sampled_user, sampled_items, sums);
    finalize_kernel<<<1, 1, 0, stream>>>(sums, out);
}

// Round 13
// 296.203 us; speedup vs baseline: 1.4447x; 1.1897x over previous
//
#include <hip/hip_runtime.h>
#include <math.h>

#define N_USERS 100000
#define N_ITEMS 40000
#define N_NODES (N_USERS + N_ITEMS)
#define EMB 128
#define EMBQ (EMB / 4)            /* 32 uints of packed 4x fp8 per row */
#define EMBH (EMB / 2)            /* 64 uints of packed 2x bf16 per row */
#define BATCH 8192
#define N_EDGES 1000000
#define ALPHA 0.1f
#define GAMMA 0.01f
#define FP8_SCALE 32.0f
#define INV_FP8_SCALE (1.0f / FP8_SCALE)

/* ---- bucket-sort CSR build geometry ---- */
#define RB_U 512                                /* rows per user bucket (shift 9) */
#define NB_U ((N_USERS + RB_U - 1) / RB_U)      /* 196 */
#define RB_I 256                                /* rows per item bucket (shift 8) */
#define NB_I ((N_ITEMS + RB_I - 1) / RB_I)      /* 157 */
#define NB_T (NB_U + NB_I)                      /* 353 */
#define PART_BLOCKS 256

#define CSRU_MAX (N_EDGES + 8 * (NB_U * RB_U))  /* u16 entries */
#define CSRI_MAX (N_EDGES + 8 * (NB_I * RB_I))  /* u32 entries */

typedef float f32x2 __attribute__((ext_vector_type(2)));

// ---------- bf16 pack/unpack (RNE) -------------------------------------------
__device__ inline unsigned int f2bf(float x) {
    const unsigned int b = __float_as_uint(x);
    return (b + 0x7FFFu + ((b >> 16) & 1u)) >> 16;
}
__device__ inline float bfl(unsigned int w) { return __uint_as_float(w << 16); }
__device__ inline float bfh(unsigned int w) { return __uint_as_float(w & 0xFFFF0000u); }

// ============ CSR build, atomic-free (block-private hist + bucket sort) =======

// ---- A: per-block bucket histograms (LDS only) -------------------------------
__global__ void bucketA(const int* __restrict__ eu, const int* __restrict__ ev,
                        int* __restrict__ histA /* [PART_BLOCKS][NB_T] */) {
    __shared__ int h[NB_T];
    for (int k = threadIdx.x; k < NB_T; k += 256) h[k] = 0;
    __syncthreads();
    const int b = blockIdx.x;
    const int beg = (int)((long long)N_EDGES * b / PART_BLOCKS);
    const int end = (int)((long long)N_EDGES * (b + 1) / PART_BLOCKS);
    for (int i = beg + threadIdx.x; i < end; i += 256) {
        const int u = __builtin_nontemporal_load(&eu[i]);
        const int v = __builtin_nontemporal_load(&ev[i]);
        atomicAdd(&h[u >> 9], 1);
        atomicAdd(&h[NB_U + (v >> 8)], 1);
    }
    __syncthreads();
    for (int k = threadIdx.x; k < NB_T; k += 256) histA[b * NB_T + k] = h[k];
}

// ---- B1: per-bucket scan over the 256 block counts (353 blocks) --------------
// woff[b][k] = exclusive prefix of histA[0..b-1][k]  (NO bucket base)
__global__ void bucketB1(const int* __restrict__ histA, int* __restrict__ woff,
                         int* __restrict__ bktCnt) {
    const int k = blockIdx.x;            // bucket id
    const int t = threadIdx.x;           // block id b = t (256 threads)
    const int lane = t & 63, wid = t >> 6;
    const int v = histA[t * NB_T + k];
    int x = v;
    #pragma unroll
    for (int off = 1; off < 64; off <<= 1) {
        const int y = __shfl_up(x, off);
        if (lane >= off) x += y;
    }
    __shared__ int wt[4];
    if (lane == 63) wt[wid] = x;
    __syncthreads();
    int wo = 0;
    for (int q = 0; q < wid; ++q) wo += wt[q];
    woff[t * NB_T + k] = wo + x - v;     // exclusive
    if (t == 255) bktCnt[k] = wo + x;
}

// ---- scan353: segmented (user|item) exclusive scan of a 353-vector -----------
__global__ void scan353(const int* __restrict__ in, int* __restrict__ base_out,
                        int* __restrict__ tot_u, int* __restrict__ tot_i) {
    const int t = threadIdx.x;           // 512 threads
    const int lane = t & 63, wid = t >> 6;  // 8 waves
    const int v = (t < NB_T) ? in[t] : 0;
    int x = v;
    #pragma unroll
    for (int off = 1; off < 64; off <<= 1) {
        const int y = __shfl_up(x, off);
        if (lane >= off) x += y;
    }
    __shared__ int wt[8];
    if (lane == 63) wt[wid] = x;
    __syncthreads();
    int wo = 0;
    for (int q = 0; q < wid; ++q) wo += wt[q];
    const int inc = wo + x;              // inclusive prefix over all
    __shared__ int uTot, aTot;
    if (t == NB_U - 1) uTot = inc;
    if (t == NB_T - 1) aTot = inc;
    __syncthreads();
    if (t < NB_U)      base_out[t] = inc - v;
    else if (t < NB_T) base_out[t] = inc - v - uTot;
    if (t == 0) {
        if (tot_u) *tot_u = uTot;
        if (tot_i) *tot_i = aTot - uTot;
    }
}

// ---- C: partition edges into bucket-contiguous arrays (packed u32) -----------
// pack user-part:  lrow(9b) | v<<9   pack item-part:  lrow(8b) | u<<8
__global__ void bucketC(const int* __restrict__ eu, const int* __restrict__ ev,
                        const int* __restrict__ woff,
                        const int* __restrict__ bktBase,
                        unsigned int* __restrict__ part_u,
                        unsigned int* __restrict__ part_i) {
    __shared__ int cur[NB_T];
    const int b = blockIdx.x;
    for (int k = threadIdx.x; k < NB_T; k += 256)
        cur[k] = woff[b * NB_T + k] + bktBase[k];
    __syncthreads();
    const int beg = (int)((long long)N_EDGES * b / PART_BLOCKS);
    const int end = (int)((long long)N_EDGES * (b + 1) / PART_BLOCKS);
    for (int i = beg + threadIdx.x; i < end; i += 256) {
        const int u = __builtin_nontemporal_load(&eu[i]);
        const int v = __builtin_nontemporal_load(&ev[i]);
        const int pu = atomicAdd(&cur[u >> 9], 1);
        part_u[pu] = (unsigned int)((u & (RB_U - 1)) | (v << 9));
        const int pi = atomicAdd(&cur[NB_U + (v >> 8)], 1);
        part_i[pi] = (unsigned int)((v & (RB_I - 1)) | (u << 8));
    }
}

// ---- D1: per-bucket row degrees -> deg, isq, padded bucket sums --------------
__global__ void csr_d1(const unsigned int* __restrict__ part_u,
                       const unsigned int* __restrict__ part_i,
                       const int* __restrict__ bktBase, const int* __restrict__ bktCnt,
                       int* __restrict__ deg, float* __restrict__ isq_u,
                       float* __restrict__ isq_i, int* __restrict__ bps) {
    const int k = blockIdx.x;
    const bool isU = (k < NB_U);
    const int R = isU ? RB_U : RB_I;
    const int row0 = isU ? k * RB_U : (k - NB_U) * RB_I;
    const int Nside = isU ? N_USERS : N_ITEMS;
    const unsigned int* part = isU ? part_u : part_i;
    const int mask = R - 1;
    __shared__ int dh[RB_U];
    for (int r = threadIdx.x; r < R; r += 256) dh[r] = 0;
    __syncthreads();
    const int base = bktBase[k], cnt = bktCnt[k];
    for (int j = threadIdx.x; j < cnt; j += 256)
        atomicAdd(&dh[part[base + j] & mask], 1);
    __syncthreads();
    const int t = threadIdx.x, lane = t & 63, wid = t >> 6;
    const int r0 = 2 * t, r1 = 2 * t + 1;
    const int d0 = (r0 < R) ? dh[r0] : 0;
    const int d1 = (r1 < R) ? dh[r1] : 0;
    const int v0 = (d0 + 7) & ~7, v1 = (d1 + 7) & ~7;
    const int s = v0 + v1;
    int x = s;
    #pragma unroll
    for (int off = 1; off < 64; off <<= 1) {
        const int y = __shfl_up(x, off);
        if (lane >= off) x += y;
    }
    __shared__ int wtot[4];
    if (lane == 63) wtot[wid] = x;
    __syncthreads();
    if (t == 0) bps[k] = wtot[0] + wtot[1] + wtot[2] + wtot[3];
    if (r0 < R && row0 + r0 < Nside) {
        deg[(isU ? 0 : N_USERS) + row0 + r0] = d0;
        if (isU) isq_u[row0 + r0] = (d0 > 0) ? (1.0f / sqrtf((float)d0)) : 0.f;
        else     isq_i[row0 + r0] = (d0 > 0) ? (1.0f / sqrtf((float)d0)) : 0.f;
    }
    if (r1 < R && row0 + r1 < Nside) {
        deg[(isU ? 0 : N_USERS) + row0 + r1] = d1;
        if (isU) isq_u[row0 + r1] = (d1 > 0) ? (1.0f / sqrtf((float)d1)) : 0.f;
        else     isq_i[row0 + r1] = (d1 > 0) ? (1.0f / sqrtf((float)d1)) : 0.f;
    }
}

// ---- D3: write row_start, padding, and rank-scatter cols (LDS atomics only) --
__global__ void csr_d3(const unsigned int* __restrict__ part_u,
                       const unsigned int* __restrict__ part_i,
                       const int* __restrict__ bktBase, const int* __restrict__ bktCnt,
                       const int* __restrict__ bcb,
                       int* __restrict__ rs_u, int* __restrict__ rs_i,
                       unsigned short* __restrict__ csr_u, int* __restrict__ csr_i) {
    const int k = blockIdx.x;
    const bool isU = (k < NB_U);
    const int R = isU ? RB_U : RB_I;
    const int row0 = isU ? k * RB_U : (k - NB_U) * RB_I;
    const int Nside = isU ? N_USERS : N_ITEMS;
    const unsigned int* part = isU ? part_u : part_i;
    const int mask = R - 1;
    const int shift = isU ? 9 : 8;
    __shared__ int dh[RB_U];
    __shared__ int cur[RB_U];
    for (int r = threadIdx.x; r < R; r += 256) dh[r] = 0;
    __syncthreads();
    const int base = bktBase[k], cnt = bktCnt[k];
    for (int j = threadIdx.x; j < cnt; j += 256)
        atomicAdd(&dh[part[base + j] & mask], 1);
    __syncthreads();
    const int t = threadIdx.x, lane = t & 63, wid = t >> 6;
    const int r0 = 2 * t, r1 = 2 * t + 1;
    const int d0 = (r0 < R) ? dh[r0] : 0;
    const int d1 = (r1 < R) ? dh[r1] : 0;
    const int v0 = (d0 + 7) & ~7, v1 = (d1 + 7) & ~7;
    const int s = v0 + v1;
    int x = s;
    #pragma unroll
    for (int off = 1; off < 64; off <<= 1) {
        const int y = __shfl_up(x, off);
        if (lane >= off) x += y;
    }
    __shared__ int wtot[4];
    if (lane == 63) wtot[wid] = x;
    __syncthreads();
    int wo = 0;
    for (int q = 0; q < wid; ++q) wo += wtot[q];
    const int pref = wo + x - s;              // exclusive padded prefix at r0
    const int cb = bcb[k];
    if (r0 < R) {
        const int st = cb + pref;
        cur[r0] = st;
        if (row0 + r0 < Nside) { if (isU) rs_u[row0 + r0] = st; else rs_i[row0 + r0] = st; }
        for (int q = d0; q < v0; ++q) {
            if (isU) csr_u[st + q] = (unsigned short)N_ITEMS; else csr_i[st + q] = N_USERS;
        }
    }
    if (r1 < R) {
        const int st = cb + pref + v0;
        cur[r1] = st;
        if (row0 + r1 < Nside) { if (isU) rs_u[row0 + r1] = st; else rs_i[row0 + r1] = st; }
        for (int q = d1; q < v1; ++q) {
            if (isU) csr_u[st + q] = (unsigned short)N_ITEMS; else csr_i[st + q] = N_USERS;
        }
    }
    __syncthreads();
    for (int j = threadIdx.x; j < cnt; j += 256) {
        const unsigned int e = part[base + j];
        const int pos = atomicAdd(&cur[e & mask], 1);
        const int col = (int)(e >> shift);
        if (isU) csr_u[pos] = (unsigned short)col; else csr_i[pos] = col;
    }
}

// ================== embedding pipeline (unchanged) ============================

__global__ void zero_rows_kernel(unsigned int* __restrict__ e0u, unsigned int* __restrict__ e1u,
                                 unsigned int* __restrict__ e2u, unsigned int* __restrict__ e3u,
                                 unsigned int* __restrict__ e0i, unsigned int* __restrict__ e1i,
                                 unsigned int* __restrict__ e2i, unsigned int* __restrict__ e3i) {
    const int t = threadIdx.x;   // 256 threads: 8 buffers x 32 words
    unsigned int* bufs[8] = {e0u, e1u, e2u, e3u, e0i, e1i, e2i, e3i};
    const int b = t >> 5;
    const size_t row = (b < 4) ? (size_t)N_USERS : (size_t)N_ITEMS;
    bufs[b][row * EMBQ + (t & 31)] = 0u;
}

__global__ void init_kernel(const float* __restrict__ user_emb,
                            const float* __restrict__ item_emb,
                            const float* __restrict__ isq_u,
                            const float* __restrict__ isq_i,
                            unsigned int* __restrict__ e0u,
                            unsigned int* __restrict__ e0i,
                            unsigned int* __restrict__ x0b) {
    const int total = N_NODES * EMBQ;
    const int utotal = N_USERS * EMBQ;
    int i = blockIdx.x * blockDim.x + threadIdx.x;
    const int stride = gridDim.x * blockDim.x;
    for (; i < total; i += stride) {
        const int node = i >> 5;
        const int q    = i & 31;
        float4 v; float n;
        if (node < N_USERS) {
            v = ((const float4*)(user_emb + (size_t)node * EMB))[q];
            n = FP8_SCALE * isq_u[node];
        } else {
            v = ((const float4*)(item_emb + (size_t)(node - N_USERS) * EMB))[q];
            n = FP8_SCALE * isq_i[node - N_USERS];
        }
        int pk = __builtin_amdgcn_cvt_pk_fp8_f32(n * v.x, n * v.y, 0, false);
        pk = __builtin_amdgcn_cvt_pk_fp8_f32(n * v.z, n * v.w, pk, true);
        if (node < N_USERS) e0u[i] = (unsigned int)pk;
        else                e0i[i - utotal] = (unsigned int)pk;
        const size_t xb = (size_t)node * EMBH + q * 2;
        x0b[xb]     = f2bf(v.x) | (f2bf(v.y) << 16);
        x0b[xb + 1] = f2bf(v.z) | (f2bf(v.w) << 16);
    }
}

__global__ void spmm_u_kernel(const unsigned int* __restrict__ cur_i,
                              unsigned int* __restrict__ nxt_u,
                              const int* __restrict__ rs_u,
                              const unsigned short* __restrict__ csr_u,
                              const float* __restrict__ isq_u) {
    const int lane = threadIdx.x & 63;
    const int half = lane >> 5;
    const int sub  = lane & 31;
    const int w = blockIdx.x * (blockDim.x >> 6) + (threadIdx.x >> 6);
    if (w >= N_USERS) return;
    const int beg = rs_u[w];
    const int end = rs_u[w + 1];
    float s0 = 0.f, s1 = 0.f, s2 = 0.f, s3 = 0.f;
    for (int j = beg + half; j < end; j += 8) {
        const int c0 = csr_u[j];
        const int c1 = csr_u[j + 2];
        const int c2 = csr_u[j + 4];
        const int c3 = csr_u[j + 6];
        const unsigned int v0 = cur_i[(size_t)c0 * EMBQ + sub];
        const unsigned int v1 = cur_i[(size_t)c1 * EMBQ + sub];
        const unsigned int v2 = cur_i[(size_t)c2 * EMBQ + sub];
        const unsigned int v3 = cur_i[(size_t)c3 * EMBQ + sub];
        const f32x2 l0 = __builtin_amdgcn_cvt_pk_f32_fp8((int)v0, false);
        const f32x2 h0 = __builtin_amdgcn_cvt_pk_f32_fp8((int)v0, true);
        const f32x2 l1 = __builtin_amdgcn_cvt_pk_f32_fp8((int)v1, false);
        const f32x2 h1 = __builtin_amdgcn_cvt_pk_f32_fp8((int)v1, true);
        const f32x2 l2 = __builtin_amdgcn_cvt_pk_f32_fp8((int)v2, false);
        const f32x2 h2 = __builtin_amdgcn_cvt_pk_f32_fp8((int)v2, true);
        const f32x2 l3 = __builtin_amdgcn_cvt_pk_f32_fp8((int)v3, false);
        const f32x2 h3 = __builtin_amdgcn_cvt_pk_f32_fp8((int)v3, true);
        s0 += (l0.x + l1.x) + (l2.x + l3.x);
        s1 += (l0.y + l1.y) + (l2.y + l3.y);
        s2 += (h0.x + h1.x) + (h2.x + h3.x);
        s3 += (h0.y + h1.y) + (h2.y + h3.y);
    }
    s0 += __shfl_down(s0, 32);
    s1 += __shfl_down(s1, 32);
    s2 += __shfl_down(s2, 32);
    s3 += __shfl_down(s3, 32);
    if (half == 0) {
        const float n = isq_u[w];
        const float sc = n * n;
        int pk = __builtin_amdgcn_cvt_pk_fp8_f32(sc * s0, sc * s1, 0, false);
        pk = __builtin_amdgcn_cvt_pk_fp8_f32(sc * s2, sc * s3, pk, true);
        nxt_u[(size_t)w * EMBQ + sub] = (unsigned int)pk;
    }
}

__global__ void spmm_i_kernel(const unsigned int* __restrict__ cur_u,
                              unsigned int* __restrict__ nxt_i,
                              const int* __restrict__ rs_i,
                              const int* __restrict__ csr_i,
                              const float* __restrict__ isq_i) {
    const int lane = threadIdx.x & 63;
    const int half = lane >> 5;
    const int sub  = lane & 31;
    const int w = blockIdx.x * (blockDim.x >> 6) + (threadIdx.x >> 6);
    if (w >= N_ITEMS) return;
    const int beg = rs_i[w];
    const int end = rs_i[w + 1];
    float s0 = 0.f, s1 = 0.f, s2 = 0.f, s3 = 0.f;
    for (int j = beg + half; j < end; j += 8) {
        const int c0 = csr_i[j];
        const int c1 = csr_i[j + 2];
        const int c2 = csr_i[j + 4];
        const int c3 = csr_i[j + 6];
        const unsigned int v0 = cur_u[(size_t)c0 * EMBQ + sub];
        const unsigned int v1 = cur_u[(size_t)c1 * EMBQ + sub];
        const unsigned int v2 = cur_u[(size_t)c2 * EMBQ + sub];
        const unsigned int v3 = cur_u[(size_t)c3 * EMBQ + sub];
        const f32x2 l0 = __builtin_amdgcn_cvt_pk_f32_fp8((int)v0, false);
        const f32x2 h0 = __builtin_amdgcn_cvt_pk_f32_fp8((int)v0, true);
        const f32x2 l1 = __builtin_amdgcn_cvt_pk_f32_fp8((int)v1, false);
        const f32x2 h1 = __builtin_amdgcn_cvt_pk_f32_fp8((int)v1, true);
        const f32x2 l2 = __builtin_amdgcn_cvt_pk_f32_fp8((int)v2, false);
        const f32x2 h2 = __builtin_amdgcn_cvt_pk_f32_fp8((int)v2, true);
        const f32x2 l3 = __builtin_amdgcn_cvt_pk_f32_fp8((int)v3, false);
        const f32x2 h3 = __builtin_amdgcn_cvt_pk_f32_fp8((int)v3, true);
        s0 += (l0.x + l1.x) + (l2.x + l3.x);
        s1 += (l0.y + l1.y) + (l2.y + l3.y);
        s2 += (h0.x + h1.x) + (h2.x + h3.x);
        s3 += (h0.y + h1.y) + (h2.y + h3.y);
    }
    s0 += __shfl_down(s0, 32);
    s1 += __shfl_down(s1, 32);
    s2 += __shfl_down(s2, 32);
    s3 += __shfl_down(s3, 32);
    if (half == 0) {
        const float n = isq_i[w];
        const float sc = n * n;
        int pk = __builtin_amdgcn_cvt_pk_fp8_f32(sc * s0, sc * s1, 0, false);
        pk = __builtin_amdgcn_cvt_pk_fp8_f32(sc * s2, sc * s3, pk, true);
        nxt_i[(size_t)w * EMBQ + sub] = (unsigned int)pk;
    }
}

__device__ inline float logsigmoidf(float x) {
    return (x >= 0.f) ? -log1pf(expf(-x)) : (x - log1pf(expf(x)));
}

__global__ void loss_kernel(const unsigned int* __restrict__ x0b,
                            const unsigned short* __restrict__ e1u,
                            const unsigned short* __restrict__ e2u,
                            const unsigned short* __restrict__ e3u,
                            const unsigned short* __restrict__ e1i,
                            const unsigned short* __restrict__ e2i,
                            const unsigned short* __restrict__ e3i,
                            const int* __restrict__ deg,
                            const int* __restrict__ users,
                            const int* __restrict__ pos_items,
                            const int* __restrict__ neg_items,
                            const int* __restrict__ sampled_user,
                            const int* __restrict__ sampled_items,
                            float* __restrict__ sums) {
    const int lane = threadIdx.x & 63;
    const int wid  = threadIdx.x >> 6;
    const int gw   = blockIdx.x * 4 + wid;
    const int nw   = gridDim.x * 4;
    float s_bce = 0.f, s_pred = 0.f, s_plogp = 0.f, s_ul = 0.f;
    for (int p = gw; p < 4 * BATCH; p += nw) {
        int u, it;
        if (p < 2 * BATCH) {
            if (p < BATCH) { u = users[p];          it = pos_items[p]; }
            else           { u = users[p - BATCH];  it = neg_items[p - BATCH]; }
        } else {
            const int q = p - 2 * BATCH;
            u = sampled_user[q]; it = sampled_items[q];
        }
        const float sdu = sqrtf((float)deg[u]) * INV_FP8_SCALE;
        const unsigned int a0 = x0b[(size_t)u * EMBH + lane];
        const size_t ui = (size_t)u * 64 + lane;
        const f32x2 u1 = __builtin_amdgcn_cvt_pk_f32_fp8((int)e1u[ui], false);
        const f32x2 u2 = __builtin_amdgcn_cvt_pk_f32_fp8((int)e2u[ui], false);
        const f32x2 u3 = __builtin_amdgcn_cvt_pk_f32_fp8((int)e3u[ui], false);
        const float ax = bfl(a0) + sdu * (u1.x + u2.x + u3.x);
        const float ay = bfh(a0) + sdu * (u1.y + u2.y + u3.y);
        const float sdi = sqrtf((float)deg[N_USERS + it]) * INV_FP8_SCALE;
        const unsigned int b0 = x0b[(size_t)(N_USERS + it) * EMBH + lane];
        const size_t ii = (size_t)it * 64 + lane;
        const f32x2 i1 = __builtin_amdgcn_cvt_pk_f32_fp8((int)e1i[ii], false);
        const f32x2 i2 = __builtin_amdgcn_cvt_pk_f32_fp8((int)e2i[ii], false);
        const f32x2 i3 = __builtin_amdgcn_cvt_pk_f32_fp8((int)e3i[ii], false);
        const float bx = bfl(b0) + sdi * (i1.x + i2.x + i3.x);
        const float by = bfh(b0) + sdi * (i1.y + i2.y + i3.y);
        float d = ax * bx + ay * by;
        #pragma unroll
        for (int off = 32; off > 0; off >>= 1) d += __shfl_down(d, off);
        if (lane == 0) {
            d *= (1.f / 16.f);
            const float pred = 1.f / (1.f + expf(-d));
            if (p < 2 * BATCH) {
                const float ls  = logsigmoidf(d);
                const float lsn = logsigmoidf(-d);
                s_bce   += (p < BATCH) ? -ls : -lsn;
                s_pred  += pred;
                s_plogp += pred * ls;
            } else {
                s_ul += pred;
            }
        }
    }
    __shared__ float red[4][4];
    if (lane == 0) {
        red[wid][0] = s_bce; red[wid][1] = s_pred;
        red[wid][2] = s_plogp; red[wid][3] = s_ul;
    }
    __syncthreads();
    if (threadIdx.x < 4) {
        const float v = red[0][threadIdx.x] + red[1][threadIdx.x]
                      + red[2][threadIdx.x] + red[3][threadIdx.x];
        atomicAdd(&sums[threadIdx.x], v);
    }
}

__global__ void finalize_kernel(const float* __restrict__ sums, float* __restrict__ out) {
    if (threadIdx.x == 0 && blockIdx.x == 0) {
        const float n = 2.f * BATCH;
        const float bce        = sums[0] / n;
        const float pred_avg   = sums[1] / n;
        const float plogp_avg  = sums[2] / n;
        const float predul_avg = sums[3] / n;
        const float info = ALPHA * (-pred_avg * logf(predul_avg)
                                    - (1.f - pred_avg) * logf(1.f - predul_avg))
                         + GAMMA * plogp_avg;
        out[0] = bce;
        out[1] = info;
    }
}

extern "C" void kernel_launch(void* const* d_in, const int* in_sizes, int n_in,
                              void* d_out, int out_size, void* d_ws, size_t ws_size,
                              hipStream_t stream) {
    const float* user_emb      = (const float*)d_in[0];
    const float* item_emb      = (const float*)d_in[1];
    const int*   edge_user     = (const int*)d_in[3];
    const int*   edge_item     = (const int*)d_in[4];
    const int*   users         = (const int*)d_in[5];
    const int*   pos_items     = (const int*)d_in[6];
    const int*   neg_items     = (const int*)d_in[7];
    const int*   sampled_user  = (const int*)d_in[8];
    const int*   sampled_items = (const int*)d_in[9];
    float* out = (float*)d_out;

    const size_t ebu = (size_t)(N_USERS + 1) * EMBQ * sizeof(unsigned int); // 12.8 MB
    const size_t ebi = (size_t)(N_ITEMS + 1) * EMBQ * sizeof(unsigned int); //  5.1 MB
    char* ws = (char*)d_ws;
    size_t off = 0;
    unsigned int* e0u = (unsigned int*)(ws + off); off += ebu;
    unsigned int* e1u = (unsigned int*)(ws + off); off += ebu;
    unsigned int* e2u = (unsigned int*)(ws + off); off += ebu;
    unsigned int* e3u = (unsigned int*)(ws + off); off += ebu;
    unsigned int* e0i = (unsigned int*)(ws + off); off += ebi;
    unsigned int* e1i = (unsigned int*)(ws + off); off += ebi;
    unsigned int* e2i = (unsigned int*)(ws + off); off += ebi;
    unsigned int* e3i = (unsigned int*)(ws + off); off += ebi;
    unsigned int* x0b = (unsigned int*)(ws + off); off += (size_t)N_NODES * EMBH * 4;
    float* sums = (float*)(ws + off); off += 256;
    int*   deg   = (int*)(ws + off); off += (size_t)N_NODES * 4;
    int*   rs_u  = (int*)(ws + off); off += (size_t)(N_USERS + 1) * 4 + 252;
    int*   rs_i  = (int*)(ws + off); off += (size_t)(N_ITEMS + 1) * 4 + 252;
    float* isq_u = (float*)(ws + off); off += (size_t)N_USERS * 4;
    float* isq_i = (float*)(ws + off); off += (size_t)N_ITEMS * 4;
    unsigned short* csr_u = (unsigned short*)(ws + off); off += (size_t)CSRU_MAX * 2 + 256;
    int*   csr_i = (int*)(ws + off); off += (size_t)CSRI_MAX * 4;
    unsigned int* part_u = (unsigned int*)(ws + off); off += (size_t)N_EDGES * 4;
    unsigned int* part_i = (unsigned int*)(ws + off); off += (size_t)N_EDGES * 4;
    int*   histA   = (int*)(ws + off); off += (size_t)PART_BLOCKS * NB_T * 4;
    int*   woff    = (int*)(ws + off); off += (size_t)PART_BLOCKS * NB_T * 4;
    int*   bktCnt  = (int*)(ws + off); off += (size_t)NB_T * 4;
    int*   bktBase = (int*)(ws + off); off += (size_t)NB_T * 4;
    int*   bps     = (int*)(ws + off); off += (size_t)NB_T * 4;
    int*   bcb     = (int*)(ws + off); off += (size_t)NB_T * 4;

    hipMemsetAsync(sums, 0, 4 * sizeof(float), stream);

    bucketA<<<PART_BLOCKS, 256, 0, stream>>>(edge_user, edge_item, histA);
    bucketB1<<<NB_T, 256, 0, stream>>>(histA, woff, bktCnt);
    scan353<<<1, 512, 0, stream>>>(bktCnt, bktBase, nullptr, nullptr);
    bucketC<<<PART_BLOCKS, 256, 0, stream>>>(edge_user, edge_item, woff, bktBase,
                                             part_u, part_i);
    csr_d1<<<NB_T, 256, 0, stream>>>(part_u, part_i, bktBase, bktCnt,
                                     deg, isq_u, isq_i, bps);
    scan353<<<1, 512, 0, stream>>>(bps, bcb, rs_u + N_USERS, rs_i + N_ITEMS);
    csr_d3<<<NB_T, 256, 0, stream>>>(part_u, part_i, bktBase, bktCnt, bcb,
                                     rs_u, rs_i, csr_u, csr_i);
    zero_rows_kernel<<<1, 256, 0, stream>>>(e0u, e1u, e2u, e3u, e0i, e1i, e2i, e3i);
    init_kernel<<<4096, 256, 0, stream>>>(user_emb, item_emb, isq_u, isq_i,
                                          e0u, e0i, x0b);

    spmm_u_kernel<<<(N_USERS + 3) / 4, 256, 0, stream>>>(e0i, e1u, rs_u, csr_u, isq_u);
    spmm_i_kernel<<<(N_ITEMS + 3) / 4, 256, 0, stream>>>(e0u, e1i, rs_i, csr_i, isq_i);
    spmm_u_kernel<<<(N_USERS + 3) / 4, 256, 0, stream>>>(e1i, e2u, rs_u, csr_u, isq_u);
    spmm_i_kernel<<<(N_ITEMS + 3) / 4, 256, 0, stream>>>(e1u, e2i, rs_i, csr_i, isq_i);
    spmm_u_kernel<<<(N_USERS + 3) / 4, 256, 0, stream>>>(e2i, e3u, rs_u, csr_u, isq_u);
    spmm_i_kernel<<<(N_ITEMS + 3) / 4, 256, 0, stream>>>(e2u, e3i, rs_i, csr_i, isq_i);

    loss_kernel<<<512, 256, 0, stream>>>(x0b,
                                         (const unsigned short*)e1u,
                                         (const unsigned short*)e2u,
                                         (const unsigned short*)e3u,
                                         (const unsigned short*)e1i,
                                         (const unsigned short*)e2i,
                                         (const unsigned short*)e3i,
                                         deg, users, pos_items, neg_items,
                                         sampled_user, sampled_items, sums);
    finalize_kernel<<<1, 1, 0, stream>>>(sums, out);
}

// Round 14
// 285.695 us; speedup vs baseline: 1.4978x; 1.0368x over previous
//
#include <hip/hip_runtime.h>
#include <math.h>

#define N_USERS 100000
#define N_ITEMS 40000
#define N_NODES (N_USERS + N_ITEMS)
#define EMB 128
#define EMBQ (EMB / 4)            /* 32 uints of packed 4x fp8 per row */
#define EMBH (EMB / 2)            /* 64 uints of packed 2x bf16 per row */
#define BATCH 8192
#define N_EDGES 1000000
#define ALPHA 0.1f
#define GAMMA 0.01f
#define FP8_SCALE 32.0f
#define INV_FP8_SCALE (1.0f / FP8_SCALE)

/* ---- bucket-sort CSR build geometry ---- */
#define RB_U 512                                /* rows per user bucket (shift 9) */
#define NB_U ((N_USERS + RB_U - 1) / RB_U)      /* 196 */
#define RB_I 256                                /* rows per item bucket (shift 8) */
#define NB_I ((N_ITEMS + RB_I - 1) / RB_I)      /* 157 */
#define NB_T (NB_U + NB_I)                      /* 353 */
#define PART_BLOCKS 256

#define CSRU_MAX (N_EDGES + 8 * (NB_U * RB_U))  /* u16 entries */
#define CSRI_MAX (N_EDGES + 8 * (NB_I * RB_I))  /* u32 entries */

#define UBLK ((N_USERS + 3) / 4)                /* 25000 user spmm blocks */
#define IBLK ((N_ITEMS + 3) / 4)                /* 10000 item spmm blocks */

typedef float f32x2 __attribute__((ext_vector_type(2)));

// ---------- bf16 pack/unpack (RNE) -------------------------------------------
__device__ inline unsigned int f2bf(float x) {
    const unsigned int b = __float_as_uint(x);
    return (b + 0x7FFFu + ((b >> 16) & 1u)) >> 16;
}
__device__ inline float bfl(unsigned int w) { return __uint_as_float(w << 16); }
__device__ inline float bfh(unsigned int w) { return __uint_as_float(w & 0xFFFF0000u); }

// ============ CSR build (block-private hist + bucket sort, no global atomics) =

// ---- A: per-block bucket histograms (LDS only) -------------------------------
__global__ void bucketA(const int* __restrict__ eu, const int* __restrict__ ev,
                        int* __restrict__ histA /* [PART_BLOCKS][NB_T] */) {
    __shared__ int h[NB_T];
    for (int k = threadIdx.x; k < NB_T; k += 256) h[k] = 0;
    __syncthreads();
    const int b = blockIdx.x;
    const int beg = (int)((long long)N_EDGES * b / PART_BLOCKS);
    const int end = (int)((long long)N_EDGES * (b + 1) / PART_BLOCKS);
    for (int i = beg + threadIdx.x; i < end; i += 256) {
        const int u = __builtin_nontemporal_load(&eu[i]);
        const int v = __builtin_nontemporal_load(&ev[i]);
        atomicAdd(&h[u >> 9], 1);
        atomicAdd(&h[NB_U + (v >> 8)], 1);
    }
    __syncthreads();
    for (int k = threadIdx.x; k < NB_T; k += 256) histA[b * NB_T + k] = h[k];
}

// ---- B1: per-bucket scan over the 256 block counts (353 blocks) --------------
__global__ void bucketB1(const int* __restrict__ histA, int* __restrict__ woff,
                         int* __restrict__ bktCnt) {
    const int k = blockIdx.x;            // bucket id
    const int t = threadIdx.x;           // block id b = t (256 threads)
    const int lane = t & 63, wid = t >> 6;
    const int v = histA[t * NB_T + k];
    int x = v;
    #pragma unroll
    for (int off = 1; off < 64; off <<= 1) {
        const int y = __shfl_up(x, off);
        if (lane >= off) x += y;
    }
    __shared__ int wt[4];
    if (lane == 63) wt[wid] = x;
    __syncthreads();
    int wo = 0;
    for (int q = 0; q < wid; ++q) wo += wt[q];
    woff[t * NB_T + k] = wo + x - v;     // exclusive (no bucket base)
    if (t == 255) bktCnt[k] = wo + x;
}

// ---- scan353: segmented (user|item) exclusive scan of a 353-vector -----------
__global__ void scan353(const int* __restrict__ in, int* __restrict__ base_out,
                        int* __restrict__ tot_u, int* __restrict__ tot_i) {
    const int t = threadIdx.x;           // 512 threads
    const int lane = t & 63, wid = t >> 6;  // 8 waves
    const int v = (t < NB_T) ? in[t] : 0;
    int x = v;
    #pragma unroll
    for (int off = 1; off < 64; off <<= 1) {
        const int y = __shfl_up(x, off);
        if (lane >= off) x += y;
    }
    __shared__ int wt[8];
    if (lane == 63) wt[wid] = x;
    __syncthreads();
    int wo = 0;
    for (int q = 0; q < wid; ++q) wo += wt[q];
    const int inc = wo + x;              // inclusive prefix over all
    __shared__ int uTot, aTot;
    if (t == NB_U - 1) uTot = inc;
    if (t == NB_T - 1) aTot = inc;
    __syncthreads();
    if (t < NB_U)      base_out[t] = inc - v;
    else if (t < NB_T) base_out[t] = inc - v - uTot;
    if (t == 0) {
        if (tot_u) *tot_u = uTot;
        if (tot_i) *tot_i = aTot - uTot;
    }
}

// ---- C: partition edges into bucket-contiguous arrays (packed u32) -----------
__global__ void bucketC(const int* __restrict__ eu, const int* __restrict__ ev,
                        const int* __restrict__ woff,
                        const int* __restrict__ bktBase,
                        unsigned int* __restrict__ part_u,
                        unsigned int* __restrict__ part_i) {
    __shared__ int cur[NB_T];
    const int b = blockIdx.x;
    for (int k = threadIdx.x; k < NB_T; k += 256)
        cur[k] = woff[b * NB_T + k] + bktBase[k];
    __syncthreads();
    const int beg = (int)((long long)N_EDGES * b / PART_BLOCKS);
    const int end = (int)((long long)N_EDGES * (b + 1) / PART_BLOCKS);
    for (int i = beg + threadIdx.x; i < end; i += 256) {
        const int u = __builtin_nontemporal_load(&eu[i]);
        const int v = __builtin_nontemporal_load(&ev[i]);
        const int pu = atomicAdd(&cur[u >> 9], 1);
        part_u[pu] = (unsigned int)((u & (RB_U - 1)) | (v << 9));
        const int pi = atomicAdd(&cur[NB_U + (v >> 8)], 1);
        part_i[pi] = (unsigned int)((v & (RB_I - 1)) | (u << 8));
    }
}

// ---- D1: per-bucket row degrees -> deg, isq, LOCAL padded row prefix, bps ----
__global__ void csr_d1(const unsigned int* __restrict__ part_u,
                       const unsigned int* __restrict__ part_i,
                       const int* __restrict__ bktBase, const int* __restrict__ bktCnt,
                       int* __restrict__ deg, float* __restrict__ isq_u,
                       float* __restrict__ isq_i,
                       int* __restrict__ rs_u, int* __restrict__ rs_i,
                       int* __restrict__ bps) {
    const int k = blockIdx.x;
    const bool isU = (k < NB_U);
    const int R = isU ? RB_U : RB_I;
    const int row0 = isU ? k * RB_U : (k - NB_U) * RB_I;
    const int Nside = isU ? N_USERS : N_ITEMS;
    const unsigned int* part = isU ? part_u : part_i;
    const int mask = R - 1;
    __shared__ int dh[RB_U];
    for (int r = threadIdx.x; r < R; r += 256) dh[r] = 0;
    __syncthreads();
    const int base = bktBase[k], cnt = bktCnt[k];
    for (int j = threadIdx.x; j < cnt; j += 256)
        atomicAdd(&dh[part[base + j] & mask], 1);
    __syncthreads();
    const int t = threadIdx.x, lane = t & 63, wid = t >> 6;
    const int r0 = 2 * t, r1 = 2 * t + 1;
    const int d0 = (r0 < R) ? dh[r0] : 0;
    const int d1 = (r1 < R) ? dh[r1] : 0;
    const int v0 = (d0 + 7) & ~7, v1 = (d1 + 7) & ~7;
    const int s = v0 + v1;
    int x = s;
    #pragma unroll
    for (int off = 1; off < 64; off <<= 1) {
        const int y = __shfl_up(x, off);
        if (lane >= off) x += y;
    }
    __shared__ int wtot[4];
    if (lane == 63) wtot[wid] = x;
    __syncthreads();
    int wo = 0;
    for (int q = 0; q < wid; ++q) wo += wtot[q];
    const int pref = wo + x - s;         // exclusive LOCAL padded prefix at r0
    if (t == 0) bps[k] = wtot[0] + wtot[1] + wtot[2] + wtot[3];
    if (r0 < R && row0 + r0 < Nside) {
        deg[(isU ? 0 : N_USERS) + row0 + r0] = d0;
        if (isU) { isq_u[row0 + r0] = (d0 > 0) ? (1.0f / sqrtf((float)d0)) : 0.f;
                   rs_u[row0 + r0] = pref; }
        else     { isq_i[row0 + r0] = (d0 > 0) ? (1.0f / sqrtf((float)d0)) : 0.f;
                   rs_i[row0 + r0] = pref; }
    }
    if (r1 < R && row0 + r1 < Nside) {
        deg[(isU ? 0 : N_USERS) + row0 + r1] = d1;
        if (isU) { isq_u[row0 + r1] = (d1 > 0) ? (1.0f / sqrtf((float)d1)) : 0.f;
                   rs_u[row0 + r1] = pref + v0; }
        else     { isq_i[row0 + r1] = (d1 > 0) ? (1.0f / sqrtf((float)d1)) : 0.f;
                   rs_i[row0 + r1] = pref + v0; }
    }
}

// ---- scatter: rs local->absolute, pad, rank-scatter (single part pass) -------
__global__ void csr_scatter(const unsigned int* __restrict__ part_u,
                            const unsigned int* __restrict__ part_i,
                            const int* __restrict__ bktBase, const int* __restrict__ bktCnt,
                            const int* __restrict__ bcb,
                            int* __restrict__ rs_u, int* __restrict__ rs_i,
                            const int* __restrict__ deg,
                            unsigned short* __restrict__ csr_u, int* __restrict__ csr_i) {
    const int k = blockIdx.x;
    const bool isU = (k < NB_U);
    const int R = isU ? RB_U : RB_I;
    const int row0 = isU ? k * RB_U : (k - NB_U) * RB_I;
    const int Nside = isU ? N_USERS : N_ITEMS;
    const unsigned int* part = isU ? part_u : part_i;
    int* rs = isU ? rs_u : rs_i;
    const int* dg = isU ? deg : deg + N_USERS;
    const int mask = R - 1;
    const int shift = isU ? 9 : 8;
    __shared__ int cur[RB_U];
    const int cb = bcb[k];
    for (int r = threadIdx.x; r < R; r += 256) {
        const int row = row0 + r;
        if (row < Nside) {
            const int st = cb + rs[row];     // absolute padded row start
            rs[row] = st;
            cur[r] = st;
            const int d = dg[row];
            const int dp = (d + 7) & ~7;
            for (int q = d; q < dp; ++q) {
                if (isU) csr_u[st + q] = (unsigned short)N_ITEMS;
                else     csr_i[st + q] = N_USERS;
            }
        } else cur[r] = 0;
    }
    __syncthreads();
    const int base = bktBase[k], cnt = bktCnt[k];
    for (int j = threadIdx.x; j < cnt; j += 256) {
        const unsigned int e = part[base + j];
        const int pos = atomicAdd(&cur[e & mask], 1);
        const int col = (int)(e >> shift);
        if (isU) csr_u[pos] = (unsigned short)col; else csr_i[pos] = col;
    }
}

// ================== embedding pipeline ========================================

// -------- init: e0{u,i} = fp8(S*isq*x0); x0b = bf16(x0); +zero dummy rows -----
__global__ void init_kernel(const float* __restrict__ user_emb,
                            const float* __restrict__ item_emb,
                            const float* __restrict__ isq_u,
                            const float* __restrict__ isq_i,
                            unsigned int* __restrict__ e0u,
                            unsigned int* __restrict__ e0i,
                            unsigned int* __restrict__ e1u,
                            unsigned int* __restrict__ e2u,
                            unsigned int* __restrict__ e3u,
                            unsigned int* __restrict__ e1i,
                            unsigned int* __restrict__ e2i,
                            unsigned int* __restrict__ e3i,
                            unsigned int* __restrict__ x0b) {
    if (blockIdx.x == 0 && threadIdx.x < 256) {
        const int t = threadIdx.x;   // 8 buffers x 32 words
        unsigned int* bufs[8] = {e0u, e1u, e2u, e3u, e0i, e1i, e2i, e3i};
        const int b = t >> 5;
        const size_t row = (b < 4) ? (size_t)N_USERS : (size_t)N_ITEMS;
        bufs[b][row * EMBQ + (t & 31)] = 0u;
    }
    const int total = N_NODES * EMBQ;
    const int utotal = N_USERS * EMBQ;
    int i = blockIdx.x * blockDim.x + threadIdx.x;
    const int stride = gridDim.x * blockDim.x;
    for (; i < total; i += stride) {
        const int node = i >> 5;
        const int q    = i & 31;
        float4 v; float n;
        if (node < N_USERS) {
            v = ((const float4*)(user_emb + (size_t)node * EMB))[q];
            n = FP8_SCALE * isq_u[node];
        } else {
            v = ((const float4*)(item_emb + (size_t)(node - N_USERS) * EMB))[q];
            n = FP8_SCALE * isq_i[node - N_USERS];
        }
        int pk = __builtin_amdgcn_cvt_pk_fp8_f32(n * v.x, n * v.y, 0, false);
        pk = __builtin_amdgcn_cvt_pk_fp8_f32(n * v.z, n * v.w, pk, true);
        if (node < N_USERS) e0u[i] = (unsigned int)pk;
        else                e0i[i - utotal] = (unsigned int)pk;
        const size_t xb = (size_t)node * EMBH + q * 2;
        x0b[xb]     = f2bf(v.x) | (f2bf(v.y) << 16);
        x0b[xb + 1] = f2bf(v.z) | (f2bf(v.w) << 16);
    }
}

// ---- fused per-layer SpMM: blocks [0,UBLK) user rows, [UBLK,UBLK+IBLK) items -
__global__ void spmm_fused(const unsigned int* __restrict__ cur_u,
                           const unsigned int* __restrict__ cur_i,
                           unsigned int* __restrict__ nxt_u,
                           unsigned int* __restrict__ nxt_i,
                           const int* __restrict__ rs_u,
                           const int* __restrict__ rs_i,
                           const unsigned short* __restrict__ csr_u,
                           const int* __restrict__ csr_i,
                           const float* __restrict__ isq_u,
                           const float* __restrict__ isq_i) {
    const int lane = threadIdx.x & 63;
    const int half = lane >> 5;
    const int sub  = lane & 31;
    const int b = blockIdx.x;
    float s0 = 0.f, s1 = 0.f, s2 = 0.f, s3 = 0.f;
    if (b < UBLK) {
        const int w = b * 4 + (threadIdx.x >> 6);
        if (w >= N_USERS) return;
        const int beg = rs_u[w];
        const int end = rs_u[w + 1];
        for (int j = beg + half; j < end; j += 8) {
            const int c0 = csr_u[j];
            const int c1 = csr_u[j + 2];
            const int c2 = csr_u[j + 4];
            const int c3 = csr_u[j + 6];
            const unsigned int v0 = cur_i[(size_t)c0 * EMBQ + sub];
            const unsigned int v1 = cur_i[(size_t)c1 * EMBQ + sub];
            const unsigned int v2 = cur_i[(size_t)c2 * EMBQ + sub];
            const unsigned int v3 = cur_i[(size_t)c3 * EMBQ + sub];
            const f32x2 l0 = __builtin_amdgcn_cvt_pk_f32_fp8((int)v0, false);
            const f32x2 h0 = __builtin_amdgcn_cvt_pk_f32_fp8((int)v0, true);
            const f32x2 l1 = __builtin_amdgcn_cvt_pk_f32_fp8((int)v1, false);
            const f32x2 h1 = __builtin_amdgcn_cvt_pk_f32_fp8((int)v1, true);
            const f32x2 l2 = __builtin_amdgcn_cvt_pk_f32_fp8((int)v2, false);
            const f32x2 h2 = __builtin_amdgcn_cvt_pk_f32_fp8((int)v2, true);
            const f32x2 l3 = __builtin_amdgcn_cvt_pk_f32_fp8((int)v3, false);
            const f32x2 h3 = __builtin_amdgcn_cvt_pk_f32_fp8((int)v3, true);
            s0 += (l0.x + l1.x) + (l2.x + l3.x);
            s1 += (l0.y + l1.y) + (l2.y + l3.y);
            s2 += (h0.x + h1.x) + (h2.x + h3.x);
            s3 += (h0.y + h1.y) + (h2.y + h3.y);
        }
        s0 += __shfl_down(s0, 32);
        s1 += __shfl_down(s1, 32);
        s2 += __shfl_down(s2, 32);
        s3 += __shfl_down(s3, 32);
        if (half == 0) {
            const float n = isq_u[w];
            const float sc = n * n;
            int pk = __builtin_amdgcn_cvt_pk_fp8_f32(sc * s0, sc * s1, 0, false);
            pk = __builtin_amdgcn_cvt_pk_fp8_f32(sc * s2, sc * s3, pk, true);
            nxt_u[(size_t)w * EMBQ + sub] = (unsigned int)pk;
        }
    } else {
        const int w = (b - UBLK) * 4 + (threadIdx.x >> 6);
        if (w >= N_ITEMS) return;
        const int beg = rs_i[w];
        const int end = rs_i[w + 1];
        for (int j = beg + half; j < end; j += 8) {
            const int c0 = csr_i[j];
            const int c1 = csr_i[j + 2];
            const int c2 = csr_i[j + 4];
            const int c3 = csr_i[j + 6];
            const unsigned int v0 = cur_u[(size_t)c0 * EMBQ + sub];
            const unsigned int v1 = cur_u[(size_t)c1 * EMBQ + sub];
            const unsigned int v2 = cur_u[(size_t)c2 * EMBQ + sub];
            const unsigned int v3 = cur_u[(size_t)c3 * EMBQ + sub];
            const f32x2 l0 = __builtin_amdgcn_cvt_pk_f32_fp8((int)v0, false);
            const f32x2 h0 = __builtin_amdgcn_cvt_pk_f32_fp8((int)v0, true);
            const f32x2 l1 = __builtin_amdgcn_cvt_pk_f32_fp8((int)v1, false);
            const f32x2 h1 = __builtin_amdgcn_cvt_pk_f32_fp8((int)v1, true);
            const f32x2 l2 = __builtin_amdgcn_cvt_pk_f32_fp8((int)v2, false);
            const f32x2 h2 = __builtin_amdgcn_cvt_pk_f32_fp8((int)v2, true);
            const f32x2 l3 = __builtin_amdgcn_cvt_pk_f32_fp8((int)v3, false);
            const f32x2 h3 = __builtin_amdgcn_cvt_pk_f32_fp8((int)v3, true);
            s0 += (l0.x + l1.x) + (l2.x + l3.x);
            s1 += (l0.y + l1.y) + (l2.y + l3.y);
            s2 += (h0.x + h1.x) + (h2.x + h3.x);
            s3 += (h0.y + h1.y) + (h2.y + h3.y);
        }
        s0 += __shfl_down(s0, 32);
        s1 += __shfl_down(s1, 32);
        s2 += __shfl_down(s2, 32);
        s3 += __shfl_down(s3, 32);
        if (half == 0) {
            const float n = isq_i[w];
            const float sc = n * n;
            int pk = __builtin_amdgcn_cvt_pk_fp8_f32(sc * s0, sc * s1, 0, false);
            pk = __builtin_amdgcn_cvt_pk_fp8_f32(sc * s2, sc * s3, pk, true);
            nxt_i[(size_t)w * EMBQ + sub] = (unsigned int)pk;
        }
    }
}

__device__ inline float logsigmoidf(float x) {
    return (x >= 0.f) ? -log1pf(expf(-x)) : (x - log1pf(expf(x)));
}

__global__ void loss_kernel(const unsigned int* __restrict__ x0b,
                            const unsigned short* __restrict__ e1u,
                            const unsigned short* __restrict__ e2u,
                            const unsigned short* __restrict__ e3u,
                            const unsigned short* __restrict__ e1i,
                            const unsigned short* __restrict__ e2i,
                            const unsigned short* __restrict__ e3i,
                            const int* __restrict__ deg,
                            const int* __restrict__ users,
                            const int* __restrict__ pos_items,
                            const int* __restrict__ neg_items,
                            const int* __restrict__ sampled_user,
                            const int* __restrict__ sampled_items,
                            float* __restrict__ sums) {
    const int lane = threadIdx.x & 63;
    const int wid  = threadIdx.x >> 6;
    const int gw   = blockIdx.x * 4 + wid;
    const int nw   = gridDim.x * 4;
    float s_bce = 0.f, s_pred = 0.f, s_plogp = 0.f, s_ul = 0.f;
    for (int p = gw; p < 4 * BATCH; p += nw) {
        int u, it;
        if (p < 2 * BATCH) {
            if (p < BATCH) { u = users[p];          it = pos_items[p]; }
            else           { u = users[p - BATCH];  it = neg_items[p - BATCH]; }
        } else {
            const int q = p - 2 * BATCH;
            u = sampled_user[q]; it = sampled_items[q];
        }
        const float sdu = sqrtf((float)deg[u]) * INV_FP8_SCALE;
        const unsigned int a0 = x0b[(size_t)u * EMBH + lane];
        const size_t ui = (size_t)u * 64 + lane;
        const f32x2 u1 = __builtin_amdgcn_cvt_pk_f32_fp8((int)e1u[ui], false);
        const f32x2 u2 = __builtin_amdgcn_cvt_pk_f32_fp8((int)e2u[ui], false);
        const f32x2 u3 = __builtin_amdgcn_cvt_pk_f32_fp8((int)e3u[ui], false);
        const float ax = bfl(a0) + sdu * (u1.x + u2.x + u3.x);
        const float ay = bfh(a0) + sdu * (u1.y + u2.y + u3.y);
        const float sdi = sqrtf((float)deg[N_USERS + it]) * INV_FP8_SCALE;
        const unsigned int b0 = x0b[(size_t)(N_USERS + it) * EMBH + lane];
        const size_t ii = (size_t)it * 64 + lane;
        const f32x2 i1 = __builtin_amdgcn_cvt_pk_f32_fp8((int)e1i[ii], false);
        const f32x2 i2 = __builtin_amdgcn_cvt_pk_f32_fp8((int)e2i[ii], false);
        const f32x2 i3 = __builtin_amdgcn_cvt_pk_f32_fp8((int)e3i[ii], false);
        const float bx = bfl(b0) + sdi * (i1.x + i2.x + i3.x);
        const float by = bfh(b0) + sdi * (i1.y + i2.y + i3.y);
        float d = ax * bx + ay * by;
        #pragma unroll
        for (int off = 32; off > 0; off >>= 1) d += __shfl_down(d, off);
        if (lane == 0) {
            d *= (1.f / 16.f);
            const float pred = 1.f / (1.f + expf(-d));
            if (p < 2 * BATCH) {
                const float ls  = logsigmoidf(d);
                const float lsn = logsigmoidf(-d);
                s_bce   += (p < BATCH) ? -ls : -lsn;
                s_pred  += pred;
                s_plogp += pred * ls;
            } else {
                s_ul += pred;
            }
        }
    }
    __shared__ float red[4][4];
    if (lane == 0) {
        red[wid][0] = s_bce; red[wid][1] = s_pred;
        red[wid][2] = s_plogp; red[wid][3] = s_ul;
    }
    __syncthreads();
    if (threadIdx.x < 4) {
        const float v = red[0][threadIdx.x] + red[1][threadIdx.x]
                      + red[2][threadIdx.x] + red[3][threadIdx.x];
        atomicAdd(&sums[threadIdx.x], v);
    }
}

__global__ void finalize_kernel(const float* __restrict__ sums, float* __restrict__ out) {
    if (threadIdx.x == 0 && blockIdx.x == 0) {
        const float n = 2.f * BATCH;
        const float bce        = sums[0] / n;
        const float pred_avg   = sums[1] / n;
        const float plogp_avg  = sums[2] / n;
        const float predul_avg = sums[3] / n;
        const float info = ALPHA * (-pred_avg * logf(predul_avg)
                                    - (1.f - pred_avg) * logf(1.f - predul_avg))
                         + GAMMA * plogp_avg;
        out[0] = bce;
        out[1] = info;
    }
}

extern "C" void kernel_launch(void* const* d_in, const int* in_sizes, int n_in,
                              void* d_out, int out_size, void* d_ws, size_t ws_size,
                              hipStream_t stream) {
    const float* user_emb      = (const float*)d_in[0];
    const float* item_emb      = (const float*)d_in[1];
    const int*   edge_user     = (const int*)d_in[3];
    const int*   edge_item     = (const int*)d_in[4];
    const int*   users         = (const int*)d_in[5];
    const int*   pos_items     = (const int*)d_in[6];
    const int*   neg_items     = (const int*)d_in[7];
    const int*   sampled_user  = (const int*)d_in[8];
    const int*   sampled_items = (const int*)d_in[9];
    float* out = (float*)d_out;

    const size_t ebu = (size_t)(N_USERS + 1) * EMBQ * sizeof(unsigned int); // 12.8 MB
    const size_t ebi = (size_t)(N_ITEMS + 1) * EMBQ * sizeof(unsigned int); //  5.1 MB
    char* ws = (char*)d_ws;
    size_t off = 0;
    unsigned int* e0u = (unsigned int*)(ws + off); off += ebu;
    unsigned int* e1u = (unsigned int*)(ws + off); off += ebu;
    unsigned int* e2u = (unsigned int*)(ws + off); off += ebu;
    unsigned int* e3u = (unsigned int*)(ws + off); off += ebu;
    unsigned int* e0i = (unsigned int*)(ws + off); off += ebi;
    unsigned int* e1i = (unsigned int*)(ws + off); off += ebi;
    unsigned int* e2i = (unsigned int*)(ws + off); off += ebi;
    unsigned int* e3i = (unsigned int*)(ws + off); off += ebi;
    unsigned int* x0b = (unsigned int*)(ws + off); off += (size_t)N_NODES * EMBH * 4;
    float* sums = (float*)(ws + off); off += 256;
    int*   deg   = (int*)(ws + off); off += (size_t)N_NODES * 4;
    int*   rs_u  = (int*)(ws + off); off += (size_t)(N_USERS + 1) * 4 + 252;
    int*   rs_i  = (int*)(ws + off); off += (size_t)(N_ITEMS + 1) * 4 + 252;
    float* isq_u = (float*)(ws + off); off += (size_t)N_USERS * 4;
    float* isq_i = (float*)(ws + off); off += (size_t)N_ITEMS * 4;
    unsigned short* csr_u = (unsigned short*)(ws + off); off += (size_t)CSRU_MAX * 2 + 256;
    int*   csr_i = (int*)(ws + off); off += (size_t)CSRI_MAX * 4;
    unsigned int* part_u = (unsigned int*)(ws + off); off += (size_t)N_EDGES * 4;
    unsigned int* part_i = (unsigned int*)(ws + off); off += (size_t)N_EDGES * 4;
    int*   histA   = (int*)(ws + off); off += (size_t)PART_BLOCKS * NB_T * 4;
    int*   woff    = (int*)(ws + off); off += (size_t)PART_BLOCKS * NB_T * 4;
    int*   bktCnt  = (int*)(ws + off); off += (size_t)NB_T * 4;
    int*   bktBase = (int*)(ws + off); off += (size_t)NB_T * 4;
    int*   bps     = (int*)(ws + off); off += (size_t)NB_T * 4;
    int*   bcb     = (int*)(ws + off); off += (size_t)NB_T * 4;

    hipMemsetAsync(sums, 0, 4 * sizeof(float), stream);

    bucketA<<<PART_BLOCKS, 256, 0, stream>>>(edge_user, edge_item, histA);
    bucketB1<<<NB_T, 256, 0, stream>>>(histA, woff, bktCnt);
    scan353<<<1, 512, 0, stream>>>(bktCnt, bktBase, nullptr, nullptr);
    bucketC<<<PART_BLOCKS, 256, 0, stream>>>(edge_user, edge_item, woff, bktBase,
                                             part_u, part_i);
    csr_d1<<<NB_T, 256, 0, stream>>>(part_u, part_i, bktBase, bktCnt,
                                     deg, isq_u, isq_i, rs_u, rs_i, bps);
    scan353<<<1, 512, 0, stream>>>(bps, bcb, rs_u + N_USERS, rs_i + N_ITEMS);
    csr_scatter<<<NB_T, 256, 0, stream>>>(part_u, part_i, bktBase, bktCnt, bcb,
                                          rs_u, rs_i, deg, csr_u, csr_i);
    init_kernel<<<4096, 256, 0, stream>>>(user_emb, item_emb, isq_u, isq_i,
                                          e0u, e0i, e1u, e2u, e3u, e1i, e2i, e3i,
                                          x0b);

    spmm_fused<<<UBLK + IBLK, 256, 0, stream>>>(e0u, e0i, e1u, e1i, rs_u, rs_i,
                                                csr_u, csr_i, isq_u, isq_i);
    spmm_fused<<<UBLK + IBLK, 256, 0, stream>>>(e1u, e1i, e2u, e2i, rs_u, rs_i,
                                                csr_u, csr_i, isq_u, isq_i);
    spmm_fused<<<UBLK + IBLK, 256, 0, stream>>>(e2u, e2i, e3u, e3i, rs_u, rs_i,
                                                csr_u, csr_i, isq_u, isq_i);

    loss_kernel<<<512, 256, 0, stream>>>(x0b,
                                         (const unsigned short*)e1u,
                                         (const unsigned short*)e2u,
                                         (const unsigned short*)e3u,
                                         (const unsigned short*)e1i,
                                         (const unsigned short*)e2i,
                                         (const unsigned short*)e3i,
                                         deg, users, pos_items, neg_items,
                                         sampled_user, sampled_items, sums);
    finalize_kernel<<<1, 1, 0, stream>>>(sums, out);
}